// Round 1
// baseline (307.155 us; speedup 1.0000x reference)
//
#include <hip/hip_runtime.h>

#define T_ 4
#define E_ 1024
#define H_ 16
#define D_ 128
#define C_ 2048
#define QK_SCALE 0.08838834764831845f

typedef short s16x8 __attribute__((ext_vector_type(8)));
typedef float f32x4 __attribute__((ext_vector_type(4)));

__device__ __forceinline__ unsigned short f2bf(float x) {
    unsigned u = __builtin_bit_cast(unsigned, x);
    u = (u + 0x7FFFu + ((u >> 16) & 1u)) >> 16;
    return (unsigned short)u;
}

__device__ __forceinline__ s16x8 cvt8(const float* __restrict__ p) {
    float4 a = *reinterpret_cast<const float4*>(p);
    float4 b = *reinterpret_cast<const float4*>(p + 4);
    s16x8 r;
    r[0] = (short)f2bf(a.x); r[1] = (short)f2bf(a.y);
    r[2] = (short)f2bf(a.z); r[3] = (short)f2bf(a.w);
    r[4] = (short)f2bf(b.x); r[5] = (short)f2bf(b.y);
    r[6] = (short)f2bf(b.z); r[7] = (short)f2bf(b.w);
    return r;
}

#define MFMA16(a, b, c) __builtin_amdgcn_mfma_f32_16x16x32_bf16((a), (b), (c), 0, 0, 0)

// ---------------- K1: QKV projection (M=4096, N=2048, K=128) ----------------
// out layout: [T][H][E][D] bf16. Q pre-scaled by 1/sqrt(D).
__global__ __launch_bounds__(256) void qkv_kernel(
    const float* __restrict__ Xq, const float* __restrict__ Xk, const float* __restrict__ Xv,
    const float* __restrict__ Wq_, const float* __restrict__ Wk_, const float* __restrict__ Wv_,
    const float* __restrict__ bq_, const float* __restrict__ bk_, const float* __restrict__ bv_,
    unsigned short* __restrict__ oq, unsigned short* __restrict__ okk, unsigned short* __restrict__ ov)
{
    const int z = blockIdx.z;
    const float* X = (z == 0) ? Xq : (z == 1) ? Xk : Xv;
    const float* W = (z == 0) ? Wq_ : (z == 1) ? Wk_ : Wv_;
    const float* Bv = (z == 0) ? bq_ : (z == 1) ? bk_ : bv_;
    unsigned short* out = (z == 0) ? oq : (z == 1) ? okk : ov;
    const float scale = (z == 0) ? QK_SCALE : 1.0f;

    const int tid = threadIdx.x;
    const int w = tid >> 6;
    const int lane = tid & 63;
    const int lr = lane & 15;
    const int lg = lane >> 4;
    const int mbase = blockIdx.x * 128 + w * 32;
    const int nbase = blockIdx.y * 128;

    // A fragments: rows mbase..mbase+31, K=128 (4 chunks of 32)
    s16x8 af[2][4];
#pragma unroll
    for (int mi = 0; mi < 2; ++mi)
#pragma unroll
        for (int kc = 0; kc < 4; ++kc)
            af[mi][kc] = cvt8(&X[(mbase + mi * 16 + lr) * D_ + kc * 32 + lg * 8]);

    f32x4 acc[2][8];
#pragma unroll
    for (int mi = 0; mi < 2; ++mi)
#pragma unroll
        for (int n = 0; n < 8; ++n) acc[mi][n] = f32x4{0.f, 0.f, 0.f, 0.f};

#pragma unroll
    for (int n = 0; n < 8; ++n) {
        s16x8 bf[4];
#pragma unroll
        for (int kc = 0; kc < 4; ++kc)
            bf[kc] = cvt8(&W[(nbase + n * 16 + lr) * D_ + kc * 32 + lg * 8]);
#pragma unroll
        for (int mi = 0; mi < 2; ++mi)
#pragma unroll
            for (int kc = 0; kc < 4; ++kc)
                acc[mi][n] = MFMA16(af[mi][kc], bf[kc], acc[mi][n]);
    }

    // epilogue: add bias, scale, store bf16 to [T][H][E][D]
#pragma unroll
    for (int n = 0; n < 8; ++n) {
        const int col = nbase + n * 16 + lr;
        const float bias = Bv[col];
        const int hh = col >> 7;
        const int dd = col & 127;
#pragma unroll
        for (int mi = 0; mi < 2; ++mi)
#pragma unroll
            for (int i = 0; i < 4; ++i) {
                const int row = mbase + mi * 16 + lg * 4 + i;
                const int tt = row >> 10;
                const int e = row & 1023;
                out[((tt * H_ + hh) * E_ + e) * D_ + dd] = f2bf((acc[mi][n][i] + bias) * scale);
            }
    }
}

// ---------------- K2: causal flash attention ----------------
// grid (T*H, E/128). Block: 256 thr = 4 waves, each wave 32 q-rows.
// Output: attended [T][E][H*D] bf16 (row-major for the output GEMM).
__global__ __launch_bounds__(256) void attn_kernel(
    const unsigned short* __restrict__ Q, const unsigned short* __restrict__ K,
    const unsigned short* __restrict__ V, unsigned short* __restrict__ O)
{
    __shared__ unsigned short K_lds[64 * 128];      // XOR-swizzled
    __shared__ unsigned short V_lds[64 * 132];      // padded stride
    __shared__ unsigned short P_lds[4][32 * 64];    // per-wave, XOR-swizzled

    const int tid = threadIdx.x;
    const int w = tid >> 6;
    const int lane = tid & 63;
    const int lr = lane & 15;
    const int lg = lane >> 4;
    const int th = blockIdx.x;
    const int t = th >> 4;
    const int h = th & 15;
    const int qblk = blockIdx.y;
    const int q0 = qblk * 128 + w * 32;

    const unsigned short* Qh = Q + th * (E_ * D_);
    const unsigned short* Kh = K + th * (E_ * D_);
    const unsigned short* Vh = V + th * (E_ * D_);

    // Q fragments in registers (already scaled by 1/sqrt(D))
    s16x8 qf[2][4];
#pragma unroll
    for (int mi = 0; mi < 2; ++mi)
#pragma unroll
        for (int kc = 0; kc < 4; ++kc)
            qf[mi][kc] = *reinterpret_cast<const s16x8*>(
                &Qh[(q0 + mi * 16 + lr) * D_ + kc * 32 + lg * 8]);

    f32x4 o[2][8];
    float mrow[2][4], lrow[2][4];
#pragma unroll
    for (int mi = 0; mi < 2; ++mi) {
#pragma unroll
        for (int n = 0; n < 8; ++n) o[mi][n] = f32x4{0.f, 0.f, 0.f, 0.f};
#pragma unroll
        for (int i = 0; i < 4; ++i) { mrow[mi][i] = -1e30f; lrow[mi][i] = 0.f; }
    }

    const int nkv = qblk * 2 + 2;
    for (int kb = 0; kb < nkv; ++kb) {
        const int kv0 = kb * 64;
        __syncthreads();
        // stage K (swizzled) and V (padded) tiles: 64x128 bf16 each
#pragma unroll
        for (int it = 0; it < 4; ++it) {
            const int f = it * 256 + tid;
            const int kk = f >> 4;
            const int d8 = (f & 15) * 8;
            s16x8 kvv = *reinterpret_cast<const s16x8*>(&Kh[(kv0 + kk) * D_ + d8]);
            *reinterpret_cast<s16x8*>(&K_lds[kk * 128 + (d8 ^ ((kk & 7) << 3))]) = kvv;
            union { s16x8 v; ushort4 h2[2]; } vu;
            vu.v = *reinterpret_cast<const s16x8*>(&Vh[(kv0 + kk) * D_ + d8]);
            ushort4* vd = reinterpret_cast<ushort4*>(&V_lds[kk * 132 + d8]);
            vd[0] = vu.h2[0];
            vd[1] = vu.h2[1];
        }
        __syncthreads();

        if (kv0 <= q0 + 31) {
            // S = Q @ K^T  (per wave: 32x64)
            f32x4 s[2][4];
#pragma unroll
            for (int ni = 0; ni < 4; ++ni) {
                s16x8 kf[4];
#pragma unroll
                for (int kc = 0; kc < 4; ++kc)
                    kf[kc] = *reinterpret_cast<const s16x8*>(
                        &K_lds[(ni * 16 + lr) * 128 + ((kc * 32 + lg * 8) ^ ((lr & 7) << 3))]);
#pragma unroll
                for (int mi = 0; mi < 2; ++mi) {
                    f32x4 a = f32x4{0.f, 0.f, 0.f, 0.f};
#pragma unroll
                    for (int kc = 0; kc < 4; ++kc) a = MFMA16(qf[mi][kc], kf[kc], a);
                    s[mi][ni] = a;
                }
            }
            // causal mask (C/D layout: col=lane&15, row=(lane>>4)*4+i)
#pragma unroll
            for (int mi = 0; mi < 2; ++mi)
#pragma unroll
                for (int i = 0; i < 4; ++i) {
                    const int qrow = q0 + mi * 16 + lg * 4 + i;
#pragma unroll
                    for (int ni = 0; ni < 4; ++ni) {
                        const int kcol = kv0 + ni * 16 + lr;
                        if (kcol > qrow) s[mi][ni][i] = -1e30f;
                    }
                }
            // online softmax (row stats replicated across the 16 lanes of a row)
#pragma unroll
            for (int mi = 0; mi < 2; ++mi)
#pragma unroll
                for (int i = 0; i < 4; ++i) {
                    float r = fmaxf(fmaxf(s[mi][0][i], s[mi][1][i]),
                                    fmaxf(s[mi][2][i], s[mi][3][i]));
                    r = fmaxf(r, __shfl_xor(r, 1));
                    r = fmaxf(r, __shfl_xor(r, 2));
                    r = fmaxf(r, __shfl_xor(r, 4));
                    r = fmaxf(r, __shfl_xor(r, 8));
                    const float mn = fmaxf(mrow[mi][i], r);
                    const float esc = __expf(mrow[mi][i] - mn);
                    mrow[mi][i] = mn;
                    float rs = 0.f;
#pragma unroll
                    for (int ni = 0; ni < 4; ++ni) {
                        const float p = __expf(s[mi][ni][i] - mn);
                        s[mi][ni][i] = p;
                        rs += p;
                    }
                    rs += __shfl_xor(rs, 1);
                    rs += __shfl_xor(rs, 2);
                    rs += __shfl_xor(rs, 4);
                    rs += __shfl_xor(rs, 8);
                    lrow[mi][i] = lrow[mi][i] * esc + rs;
#pragma unroll
                    for (int n = 0; n < 8; ++n) o[mi][n][i] *= esc;
                }
            // P -> per-wave LDS (bf16, swizzled) to reach A-fragment layout
#pragma unroll
            for (int mi = 0; mi < 2; ++mi)
#pragma unroll
                for (int i = 0; i < 4; ++i) {
                    const int pr = mi * 16 + lg * 4 + i;
                    const int key = (pr & 7) << 3;
#pragma unroll
                    for (int ni = 0; ni < 4; ++ni)
                        P_lds[w][pr * 64 + ((ni * 16 + lr) ^ key)] = f2bf(s[mi][ni][i]);
                }
            // O += P @ V
#pragma unroll
            for (int kc = 0; kc < 2; ++kc) {
                s16x8 pa[2];
#pragma unroll
                for (int mi = 0; mi < 2; ++mi)
                    pa[mi] = *reinterpret_cast<const s16x8*>(
                        &P_lds[w][(mi * 16 + lr) * 64 + ((kc * 32 + lg * 8) ^ ((lr & 7) << 3))]);
#pragma unroll
                for (int n = 0; n < 8; ++n) {
                    union { s16x8 v; short u[8]; } vb;
#pragma unroll
                    for (int j = 0; j < 8; ++j)
                        vb.u[j] = (short)V_lds[(kc * 32 + lg * 8 + j) * 132 + n * 16 + lr];
                    o[0][n] = MFMA16(pa[0], vb.v, o[0][n]);
                    o[1][n] = MFMA16(pa[1], vb.v, o[1][n]);
                }
            }
        }
    }

    // epilogue: normalize and store attended [t][e][h*128+d]
    unsigned short* Ob = O + (size_t)t * E_ * C_ + h * D_;
#pragma unroll
    for (int mi = 0; mi < 2; ++mi) {
        float rcp[4];
#pragma unroll
        for (int i = 0; i < 4; ++i) rcp[i] = 1.0f / lrow[mi][i];
#pragma unroll
        for (int n = 0; n < 8; ++n)
#pragma unroll
            for (int i = 0; i < 4; ++i) {
                const int e = q0 + mi * 16 + lg * 4 + i;
                Ob[(size_t)e * C_ + n * 16 + lr] = f2bf(o[mi][n][i] * rcp[i]);
            }
    }
}

// ---------------- K3: output projection (M=4096, N=128, K=2048) ----------------
__global__ __launch_bounds__(256) void oproj_kernel(
    const unsigned short* __restrict__ A, const float* __restrict__ Wo,
    const float* __restrict__ bo, float* __restrict__ out)
{
    __shared__ unsigned short Wt[128 * 128];  // [n][k] bf16, XOR-swizzled

    const int tid = threadIdx.x;
    const int w = tid >> 6;
    const int lane = tid & 63;
    const int lr = lane & 15;
    const int lg = lane >> 4;
    const int mbase = blockIdx.x * 64 + w * 16;

    f32x4 acc[8];
#pragma unroll
    for (int n = 0; n < 8; ++n) acc[n] = f32x4{0.f, 0.f, 0.f, 0.f};

    for (int kb = 0; kb < 16; ++kb) {
        __syncthreads();
        // stage Wo[:, kb*128 : kb*128+128] -> bf16 LDS (swizzled)
#pragma unroll
        for (int it = 0; it < 16; ++it) {
            const int f = it * 256 + tid;
            const int n = f >> 5;
            const int k4 = (f & 31) * 4;
            float4 v = *reinterpret_cast<const float4*>(&Wo[n * C_ + kb * 128 + k4]);
            ushort4 hh;
            hh.x = f2bf(v.x); hh.y = f2bf(v.y); hh.z = f2bf(v.z); hh.w = f2bf(v.w);
            *reinterpret_cast<ushort4*>(&Wt[n * 128 + (k4 ^ ((n & 7) << 3))]) = hh;
        }
        __syncthreads();

        s16x8 af[4];
#pragma unroll
        for (int kc = 0; kc < 4; ++kc)
            af[kc] = *reinterpret_cast<const s16x8*>(
                &A[(mbase + lr) * C_ + kb * 128 + kc * 32 + lg * 8]);
#pragma unroll
        for (int n = 0; n < 8; ++n)
#pragma unroll
            for (int kc = 0; kc < 4; ++kc) {
                s16x8 bf = *reinterpret_cast<const s16x8*>(
                    &Wt[(n * 16 + lr) * 128 + ((kc * 32 + lg * 8) ^ ((lr & 7) << 3))]);
                acc[n] = MFMA16(af[kc], bf, acc[n]);
            }
    }

#pragma unroll
    for (int n = 0; n < 8; ++n) {
        const int col = n * 16 + lr;
        const float bias = bo[col];
#pragma unroll
        for (int i = 0; i < 4; ++i) {
            const int row = mbase + lg * 4 + i;
            out[row * D_ + col] = acc[n][i] + bias;
        }
    }
}

extern "C" void kernel_launch(void* const* d_in, const int* in_sizes, int n_in,
                              void* d_out, int out_size, void* d_ws, size_t ws_size,
                              hipStream_t stream) {
    const float* key   = (const float*)d_in[0];
    const float* value = (const float*)d_in[1];
    const float* query = (const float*)d_in[2];
    const float* Wq = (const float*)d_in[3];
    const float* bq = (const float*)d_in[4];
    const float* Wk = (const float*)d_in[5];
    const float* bk = (const float*)d_in[6];
    const float* Wv = (const float*)d_in[7];
    const float* bv = (const float*)d_in[8];
    const float* Wo = (const float*)d_in[9];
    const float* bo = (const float*)d_in[10];
    float* out = (float*)d_out;

    unsigned short* ws = (unsigned short*)d_ws;
    const size_t QKV_ELEMS = (size_t)T_ * H_ * E_ * D_;  // 8388608
    unsigned short* q_ws = ws;
    unsigned short* k_ws = ws + QKV_ELEMS;
    unsigned short* v_ws = ws + 2 * QKV_ELEMS;
    unsigned short* att_ws = ws + 3 * QKV_ELEMS;

    qkv_kernel<<<dim3(32, 16, 3), 256, 0, stream>>>(query, key, value,
                                                    Wq, Wk, Wv, bq, bk, bv,
                                                    q_ws, k_ws, v_ws);
    attn_kernel<<<dim3(64, 8), 256, 0, stream>>>(q_ws, k_ws, v_ws, att_ws);
    oproj_kernel<<<dim3(64), 256, 0, stream>>>(att_ws, Wo, bo, out);
}

// Round 2
// 172.749 us; speedup vs baseline: 1.7780x; 1.7780x over previous
//
#include <hip/hip_runtime.h>

#define T_ 4
#define E_ 1024
#define H_ 16
#define D_ 128
#define C_ 2048
#define QK_SCALE 0.08838834764831845f

typedef short s16x8 __attribute__((ext_vector_type(8)));
typedef float f32x4 __attribute__((ext_vector_type(4)));

__device__ __forceinline__ unsigned short f2bf(float x) {
    unsigned u = __builtin_bit_cast(unsigned, x);
    u = (u + 0x7FFFu + ((u >> 16) & 1u)) >> 16;
    return (unsigned short)u;
}

__device__ __forceinline__ s16x8 cvt8(const float* __restrict__ p) {
    float4 a = *reinterpret_cast<const float4*>(p);
    float4 b = *reinterpret_cast<const float4*>(p + 4);
    s16x8 r;
    r[0] = (short)f2bf(a.x); r[1] = (short)f2bf(a.y);
    r[2] = (short)f2bf(a.z); r[3] = (short)f2bf(a.w);
    r[4] = (short)f2bf(b.x); r[5] = (short)f2bf(b.y);
    r[6] = (short)f2bf(b.z); r[7] = (short)f2bf(b.w);
    return r;
}

#define MFMA16(a, b, c) __builtin_amdgcn_mfma_f32_16x16x32_bf16((a), (b), (c), 0, 0, 0)

// ---------------- K1: QKV projection (M=4096, N=2048, K=128) ----------------
// out layout: [T][H][E][D] bf16. Q pre-scaled by 1/sqrt(D).
__global__ __launch_bounds__(256) void qkv_kernel(
    const float* __restrict__ Xq, const float* __restrict__ Xk, const float* __restrict__ Xv,
    const float* __restrict__ Wq_, const float* __restrict__ Wk_, const float* __restrict__ Wv_,
    const float* __restrict__ bq_, const float* __restrict__ bk_, const float* __restrict__ bv_,
    unsigned short* __restrict__ oq, unsigned short* __restrict__ okk, unsigned short* __restrict__ ov)
{
    const int z = blockIdx.z;
    const float* X = (z == 0) ? Xq : (z == 1) ? Xk : Xv;
    const float* W = (z == 0) ? Wq_ : (z == 1) ? Wk_ : Wv_;
    const float* Bv = (z == 0) ? bq_ : (z == 1) ? bk_ : bv_;
    unsigned short* out = (z == 0) ? oq : (z == 1) ? okk : ov;
    const float scale = (z == 0) ? QK_SCALE : 1.0f;

    const int tid = threadIdx.x;
    const int w = tid >> 6;
    const int lane = tid & 63;
    const int lr = lane & 15;
    const int lg = lane >> 4;
    const int mbase = blockIdx.x * 128 + w * 32;
    const int nbase = blockIdx.y * 128;

    s16x8 af[2][4];
#pragma unroll
    for (int mi = 0; mi < 2; ++mi)
#pragma unroll
        for (int kc = 0; kc < 4; ++kc)
            af[mi][kc] = cvt8(&X[(mbase + mi * 16 + lr) * D_ + kc * 32 + lg * 8]);

    f32x4 acc[2][8];
#pragma unroll
    for (int mi = 0; mi < 2; ++mi)
#pragma unroll
        for (int n = 0; n < 8; ++n) acc[mi][n] = f32x4{0.f, 0.f, 0.f, 0.f};

#pragma unroll
    for (int n = 0; n < 8; ++n) {
        s16x8 bf[4];
#pragma unroll
        for (int kc = 0; kc < 4; ++kc)
            bf[kc] = cvt8(&W[(nbase + n * 16 + lr) * D_ + kc * 32 + lg * 8]);
#pragma unroll
        for (int mi = 0; mi < 2; ++mi)
#pragma unroll
            for (int kc = 0; kc < 4; ++kc)
                acc[mi][n] = MFMA16(af[mi][kc], bf[kc], acc[mi][n]);
    }

#pragma unroll
    for (int n = 0; n < 8; ++n) {
        const int col = nbase + n * 16 + lr;
        const float bias = Bv[col];
        const int hh = col >> 7;
        const int dd = col & 127;
#pragma unroll
        for (int mi = 0; mi < 2; ++mi)
#pragma unroll
            for (int i = 0; i < 4; ++i) {
                const int row = mbase + mi * 16 + lg * 4 + i;
                const int tt = row >> 10;
                const int e = row & 1023;
                out[((tt * H_ + hh) * E_ + e) * D_ + dd] = f2bf((acc[mi][n][i] + bias) * scale);
            }
    }
}

// ---------------- K2: causal flash attention ----------------
// grid (T*H, E/128). Block: 256 thr = 4 waves, each wave 32 q-rows.
// V staged TRANSPOSED in LDS so PV B-fragments are single ds_read_b128.
__global__ __launch_bounds__(256) void attn_kernel(
    const unsigned short* __restrict__ Q, const unsigned short* __restrict__ K,
    const unsigned short* __restrict__ V, unsigned short* __restrict__ O)
{
    __shared__ unsigned short K_lds[64 * 128];   // XOR-swizzled, key (kk&7)<<3 on d
    __shared__ unsigned short Vt_lds[128 * 64];  // [d][kv], key ((d^(d>>3))&7)<<3 on kv
    __shared__ unsigned short P_lds[4][32 * 64]; // per-wave, key (pr&7)<<3

    const int tid = threadIdx.x;
    const int w = tid >> 6;
    const int lane = tid & 63;
    const int lr = lane & 15;
    const int lg = lane >> 4;
    const int th = blockIdx.x;
    const int t = th >> 4;
    const int h = th & 15;
    const int qblk = 7 - blockIdx.y;  // longest blocks launch first (LPT packing)
    const int q0 = qblk * 128 + w * 32;

    const unsigned short* Qh = Q + th * (E_ * D_);
    const unsigned short* Kh = K + th * (E_ * D_);
    const unsigned short* Vh = V + th * (E_ * D_);

    s16x8 qf[2][4];
#pragma unroll
    for (int mi = 0; mi < 2; ++mi)
#pragma unroll
        for (int kc = 0; kc < 4; ++kc)
            qf[mi][kc] = *reinterpret_cast<const s16x8*>(
                &Qh[(q0 + mi * 16 + lr) * D_ + kc * 32 + lg * 8]);

    f32x4 o[2][8];
    float mrow[2][4], lrow[2][4];
#pragma unroll
    for (int mi = 0; mi < 2; ++mi) {
#pragma unroll
        for (int n = 0; n < 8; ++n) o[mi][n] = f32x4{0.f, 0.f, 0.f, 0.f};
#pragma unroll
        for (int i = 0; i < 4; ++i) { mrow[mi][i] = -1e30f; lrow[mi][i] = 0.f; }
    }

    const int nkv = qblk * 2 + 2;
    for (int kb = 0; kb < nkv; ++kb) {
        const int kv0 = kb * 64;
        __syncthreads();
#pragma unroll
        for (int it = 0; it < 4; ++it) {
            const int f = it * 256 + tid;
            const int kk = f >> 4;          // kv row 0..63
            const int d8 = (f & 15) * 8;    // d offset
            s16x8 kvv = *reinterpret_cast<const s16x8*>(&Kh[(kv0 + kk) * D_ + d8]);
            *reinterpret_cast<s16x8*>(&K_lds[kk * 128 + (d8 ^ ((kk & 7) << 3))]) = kvv;
            union { s16x8 v; unsigned short u[8]; } vu;
            vu.v = *reinterpret_cast<const s16x8*>(&Vh[(kv0 + kk) * D_ + d8]);
#pragma unroll
            for (int j = 0; j < 8; ++j) {
                const int d = d8 + j;
                Vt_lds[d * 64 + (kk ^ (((d ^ (d >> 3)) & 7) << 3))] = vu.u[j];
            }
        }
        __syncthreads();

        if (kv0 <= q0 + 31) {
            // S = Q @ K^T  (per wave: 32x64)
            f32x4 s[2][4];
#pragma unroll
            for (int ni = 0; ni < 4; ++ni) {
                s16x8 kf[4];
#pragma unroll
                for (int kc = 0; kc < 4; ++kc)
                    kf[kc] = *reinterpret_cast<const s16x8*>(
                        &K_lds[(ni * 16 + lr) * 128 + ((kc * 32 + lg * 8) ^ ((lr & 7) << 3))]);
#pragma unroll
                for (int mi = 0; mi < 2; ++mi) {
                    f32x4 a = f32x4{0.f, 0.f, 0.f, 0.f};
#pragma unroll
                    for (int kc = 0; kc < 4; ++kc) a = MFMA16(qf[mi][kc], kf[kc], a);
                    s[mi][ni] = a;
                }
            }
            // causal mask (C/D layout: col=lane&15, row=(lane>>4)*4+i)
#pragma unroll
            for (int mi = 0; mi < 2; ++mi)
#pragma unroll
                for (int i = 0; i < 4; ++i) {
                    const int qrow = q0 + mi * 16 + lg * 4 + i;
#pragma unroll
                    for (int ni = 0; ni < 4; ++ni) {
                        const int kcol = kv0 + ni * 16 + lr;
                        if (kcol > qrow) s[mi][ni][i] = -1e30f;
                    }
                }
            // online softmax
#pragma unroll
            for (int mi = 0; mi < 2; ++mi)
#pragma unroll
                for (int i = 0; i < 4; ++i) {
                    float r = fmaxf(fmaxf(s[mi][0][i], s[mi][1][i]),
                                    fmaxf(s[mi][2][i], s[mi][3][i]));
                    r = fmaxf(r, __shfl_xor(r, 1));
                    r = fmaxf(r, __shfl_xor(r, 2));
                    r = fmaxf(r, __shfl_xor(r, 4));
                    r = fmaxf(r, __shfl_xor(r, 8));
                    const float mn = fmaxf(mrow[mi][i], r);
                    const float esc = __expf(mrow[mi][i] - mn);
                    mrow[mi][i] = mn;
                    float rs = 0.f;
#pragma unroll
                    for (int ni = 0; ni < 4; ++ni) {
                        const float p = __expf(s[mi][ni][i] - mn);
                        s[mi][ni][i] = p;
                        rs += p;
                    }
                    rs += __shfl_xor(rs, 1);
                    rs += __shfl_xor(rs, 2);
                    rs += __shfl_xor(rs, 4);
                    rs += __shfl_xor(rs, 8);
                    lrow[mi][i] = lrow[mi][i] * esc + rs;
#pragma unroll
                    for (int n = 0; n < 8; ++n) o[mi][n][i] *= esc;
                }
            // P -> per-wave LDS (bf16, swizzled) to reach A-fragment layout
#pragma unroll
            for (int mi = 0; mi < 2; ++mi)
#pragma unroll
                for (int i = 0; i < 4; ++i) {
                    const int pr = mi * 16 + lg * 4 + i;
                    const int key = (pr & 7) << 3;
#pragma unroll
                    for (int ni = 0; ni < 4; ++ni)
                        P_lds[w][pr * 64 + ((ni * 16 + lr) ^ key)] = f2bf(s[mi][ni][i]);
                }
            // O += P @ V   (B-frags now single b128 reads from Vt)
#pragma unroll
            for (int kc = 0; kc < 2; ++kc) {
                s16x8 pa[2];
#pragma unroll
                for (int mi = 0; mi < 2; ++mi)
                    pa[mi] = *reinterpret_cast<const s16x8*>(
                        &P_lds[w][(mi * 16 + lr) * 64 + ((kc * 32 + lg * 8) ^ ((lr & 7) << 3))]);
#pragma unroll
                for (int n = 0; n < 8; ++n) {
                    const int d = n * 16 + lr;
                    const int key = ((d ^ (d >> 3)) & 7) << 3;
                    s16x8 vb = *reinterpret_cast<const s16x8*>(
                        &Vt_lds[d * 64 + ((kc * 32 + lg * 8) ^ key)]);
                    o[0][n] = MFMA16(pa[0], vb, o[0][n]);
                    o[1][n] = MFMA16(pa[1], vb, o[1][n]);
                }
            }
        }
    }

    // epilogue: normalize and store attended [t][e][h*128+d]
    unsigned short* Ob = O + (size_t)t * E_ * C_ + h * D_;
#pragma unroll
    for (int mi = 0; mi < 2; ++mi) {
        float rcp[4];
#pragma unroll
        for (int i = 0; i < 4; ++i) rcp[i] = 1.0f / lrow[mi][i];
#pragma unroll
        for (int n = 0; n < 8; ++n)
#pragma unroll
            for (int i = 0; i < 4; ++i) {
                const int e = q0 + mi * 16 + lg * 4 + i;
                Ob[(size_t)e * C_ + n * 16 + lr] = f2bf(o[mi][n][i] * rcp[i]);
            }
    }
}

// ---------------- Wo fp32 -> bf16 ----------------
__global__ __launch_bounds__(256) void wconv_kernel(
    const float* __restrict__ Wo, unsigned short* __restrict__ Wo16)
{
    const int i = (blockIdx.x * 256 + threadIdx.x) * 8;
    float4 a = *reinterpret_cast<const float4*>(Wo + i);
    float4 b = *reinterpret_cast<const float4*>(Wo + i + 4);
    s16x8 r;
    r[0] = (short)f2bf(a.x); r[1] = (short)f2bf(a.y);
    r[2] = (short)f2bf(a.z); r[3] = (short)f2bf(a.w);
    r[4] = (short)f2bf(b.x); r[5] = (short)f2bf(b.y);
    r[6] = (short)f2bf(b.z); r[7] = (short)f2bf(b.w);
    *reinterpret_cast<s16x8*>(Wo16 + i) = r;
}

// ---------------- K3: output projection (M=4096, N=128, K=2048) ----------------
// 256 blocks x 4 waves; wave w -> cols [w*32, w*32+32). No LDS, no barriers.
__global__ __launch_bounds__(256) void oproj_kernel(
    const unsigned short* __restrict__ A, const unsigned short* __restrict__ Wo16,
    const float* __restrict__ bo, float* __restrict__ out)
{
    const int tid = threadIdx.x;
    const int w = tid >> 6;
    const int lane = tid & 63;
    const int lr = lane & 15;
    const int lg = lane >> 4;
    const int mbase = blockIdx.x * 16;
    const int ncol = w * 32;

    f32x4 acc0 = f32x4{0.f, 0.f, 0.f, 0.f};
    f32x4 acc1 = f32x4{0.f, 0.f, 0.f, 0.f};
    const unsigned short* Arow = A + (size_t)(mbase + lr) * C_;
    const unsigned short* W0 = Wo16 + (size_t)(ncol + lr) * C_;
    const unsigned short* W1 = Wo16 + (size_t)(ncol + 16 + lr) * C_;

#pragma unroll 4
    for (int kb = 0; kb < 64; ++kb) {
        const int ko = kb * 32 + lg * 8;
        s16x8 af = *reinterpret_cast<const s16x8*>(Arow + ko);
        s16x8 b0 = *reinterpret_cast<const s16x8*>(W0 + ko);
        s16x8 b1 = *reinterpret_cast<const s16x8*>(W1 + ko);
        acc0 = MFMA16(af, b0, acc0);
        acc1 = MFMA16(af, b1, acc1);
    }

#pragma unroll
    for (int n = 0; n < 2; ++n) {
        const f32x4 acc = n ? acc1 : acc0;
        const int col = ncol + n * 16 + lr;
        const float bias = bo[col];
#pragma unroll
        for (int i = 0; i < 4; ++i)
            out[(mbase + lg * 4 + i) * D_ + col] = acc[i] + bias;
    }
}

extern "C" void kernel_launch(void* const* d_in, const int* in_sizes, int n_in,
                              void* d_out, int out_size, void* d_ws, size_t ws_size,
                              hipStream_t stream) {
    const float* key   = (const float*)d_in[0];
    const float* value = (const float*)d_in[1];
    const float* query = (const float*)d_in[2];
    const float* Wq = (const float*)d_in[3];
    const float* bq = (const float*)d_in[4];
    const float* Wk = (const float*)d_in[5];
    const float* bk = (const float*)d_in[6];
    const float* Wv = (const float*)d_in[7];
    const float* bv = (const float*)d_in[8];
    const float* Wo = (const float*)d_in[9];
    const float* bo = (const float*)d_in[10];
    float* out = (float*)d_out;

    unsigned short* ws = (unsigned short*)d_ws;
    const size_t QKV_ELEMS = (size_t)T_ * H_ * E_ * D_;  // 8388608
    unsigned short* q_ws = ws;
    unsigned short* k_ws = ws + QKV_ELEMS;
    unsigned short* v_ws = ws + 2 * QKV_ELEMS;
    unsigned short* att_ws = ws + 3 * QKV_ELEMS;
    unsigned short* wo16_ws = q_ws;  // q_ws is dead after attn_kernel

    qkv_kernel<<<dim3(32, 16, 3), 256, 0, stream>>>(query, key, value,
                                                    Wq, Wk, Wv, bq, bk, bv,
                                                    q_ws, k_ws, v_ws);
    attn_kernel<<<dim3(64, 8), 256, 0, stream>>>(q_ws, k_ws, v_ws, att_ws);
    wconv_kernel<<<dim3(128), 256, 0, stream>>>(Wo, wo16_ws);
    oproj_kernel<<<dim3(256), 256, 0, stream>>>(att_ws, wo16_ws, bo, out);
}

// Round 4
// 154.975 us; speedup vs baseline: 1.9820x; 1.1147x over previous
//
#include <hip/hip_runtime.h>

#define T_ 4
#define E_ 1024
#define H_ 16
#define D_ 128
#define C_ 2048
#define QK_SCALE 0.08838834764831845f

typedef short s16x8 __attribute__((ext_vector_type(8)));
typedef float f32x4 __attribute__((ext_vector_type(4)));

__device__ __forceinline__ unsigned short f2bf(float x) {
    unsigned u = __builtin_bit_cast(unsigned, x);
    u = (u + 0x7FFFu + ((u >> 16) & 1u)) >> 16;
    return (unsigned short)u;
}

#define MFMA16(a, b, c) __builtin_amdgcn_mfma_f32_16x16x32_bf16((a), (b), (c), 0, 0, 0)

__device__ __forceinline__ void gload_lds16(const unsigned short* g, unsigned short* l) {
    __builtin_amdgcn_global_load_lds(
        (const __attribute__((address_space(1))) unsigned int*)g,
        (__attribute__((address_space(3))) unsigned int*)l, 16, 0, 0);
}

// ---------------- f32 -> bf16 bulk convert (2048 elems / block) ----------------
__global__ __launch_bounds__(256) void cvt_kernel(
    const float* __restrict__ src, unsigned short* __restrict__ dst)
{
    const int i = (blockIdx.x * 256 + threadIdx.x) * 8;
    float4 a = *reinterpret_cast<const float4*>(src + i);
    float4 b = *reinterpret_cast<const float4*>(src + i + 4);
    s16x8 r;
    r[0] = (short)f2bf(a.x); r[1] = (short)f2bf(a.y);
    r[2] = (short)f2bf(a.z); r[3] = (short)f2bf(a.w);
    r[4] = (short)f2bf(b.x); r[5] = (short)f2bf(b.y);
    r[6] = (short)f2bf(b.z); r[7] = (short)f2bf(b.w);
    *reinterpret_cast<s16x8*>(dst + i) = r;
}

// ---------------- K1: QKV projection (bf16 in, bf16 out) ----------------
// Q,K out: [T][H][E][D].  V out: TRANSPOSED [T][H][D][E].  Q pre-scaled.
__global__ __launch_bounds__(256) void qkv_kernel(
    const unsigned short* __restrict__ Xq, const unsigned short* __restrict__ Xk,
    const unsigned short* __restrict__ Xv,
    const unsigned short* __restrict__ Wq_, const unsigned short* __restrict__ Wk_,
    const unsigned short* __restrict__ Wv_,
    const float* __restrict__ bq_, const float* __restrict__ bk_, const float* __restrict__ bv_,
    unsigned short* __restrict__ oq, unsigned short* __restrict__ okk,
    unsigned short* __restrict__ ov)
{
    __shared__ unsigned short Tile[128 * 136];

    const int z = blockIdx.z;
    const unsigned short* X = (z == 0) ? Xq : (z == 1) ? Xk : Xv;
    const unsigned short* W = (z == 0) ? Wq_ : (z == 1) ? Wk_ : Wv_;
    const float* Bv = (z == 0) ? bq_ : (z == 1) ? bk_ : bv_;
    unsigned short* out = (z == 0) ? oq : (z == 1) ? okk : ov;
    const float scale = (z == 0) ? QK_SCALE : 1.0f;

    const int tid = threadIdx.x;
    const int w = tid >> 6;
    const int lane = tid & 63;
    const int lr = lane & 15;
    const int lg = lane >> 4;
    const int mbase = blockIdx.x * 128 + w * 32;
    const int nbase = blockIdx.y * 128;

    s16x8 af[2][4];
#pragma unroll
    for (int mi = 0; mi < 2; ++mi)
#pragma unroll
        for (int kc = 0; kc < 4; ++kc)
            af[mi][kc] = *reinterpret_cast<const s16x8*>(
                &X[(mbase + mi * 16 + lr) * D_ + kc * 32 + lg * 8]);

    f32x4 acc[2][8];
#pragma unroll
    for (int mi = 0; mi < 2; ++mi)
#pragma unroll
        for (int n = 0; n < 8; ++n) acc[mi][n] = f32x4{0.f, 0.f, 0.f, 0.f};

#pragma unroll
    for (int n = 0; n < 8; ++n) {
        s16x8 bf[4];
#pragma unroll
        for (int kc = 0; kc < 4; ++kc)
            bf[kc] = *reinterpret_cast<const s16x8*>(
                &W[(nbase + n * 16 + lr) * D_ + kc * 32 + lg * 8]);
#pragma unroll
        for (int mi = 0; mi < 2; ++mi)
#pragma unroll
            for (int kc = 0; kc < 4; ++kc)
                acc[mi][n] = MFMA16(af[mi][kc], bf[kc], acc[mi][n]);
    }

    // bias + scale -> LDS tile (block-local 128x128, pitch 136)
#pragma unroll
    for (int n = 0; n < 8; ++n) {
        const float bias = Bv[nbase + n * 16 + lr];
#pragma unroll
        for (int mi = 0; mi < 2; ++mi)
#pragma unroll
            for (int i = 0; i < 4; ++i) {
                const int rowl = w * 32 + mi * 16 + lg * 4 + i;
                const unsigned short vv = f2bf((acc[mi][n][i] + bias) * scale);
                if (z < 2) Tile[rowl * 136 + n * 16 + lr] = vv;
                else       Tile[(n * 16 + lr) * 136 + rowl] = vv;
            }
    }
    __syncthreads();

    // coalesced write-out: thread (r, seg) stores 64 elements (8 x b128)
    const int t = (blockIdx.x * 128) >> 10;
    const int e0 = (blockIdx.x * 128) & 1023;
    const int hh = blockIdx.y;
    const int r = tid >> 1;
    const int seg = tid & 1;
    if (z < 2) {
        unsigned short* dst = out + (((size_t)(t * H_ + hh) * E_ + e0) * D_)
                              + (size_t)r * D_ + seg * 64;
#pragma unroll
        for (int j = 0; j < 8; ++j)
            *reinterpret_cast<s16x8*>(dst + j * 8) =
                *reinterpret_cast<const s16x8*>(&Tile[r * 136 + seg * 64 + j * 8]);
    } else {
        unsigned short* dst = out + (((size_t)(t * H_ + hh) * D_ + r) * E_)
                              + e0 + seg * 64;
#pragma unroll
        for (int j = 0; j < 8; ++j)
            *reinterpret_cast<s16x8*>(dst + j * 8) =
                *reinterpret_cast<const s16x8*>(&Tile[r * 136 + seg * 64 + j * 8]);
    }
}

// ---------------- K2: causal flash attention ----------------
// grid (T*H, 4). 512 thr = 8 waves: waves 0-3 -> qblk 7-p, waves 4-7 -> qblk p
// (balanced: every block computes exactly 18 tile-passes). K and Vt staged via
// global_load_lds with pre-swizzled source, double-buffered, 1 barrier/tile.
__global__ __launch_bounds__(512, 2) void attn_kernel(
    const unsigned short* __restrict__ Q, const unsigned short* __restrict__ K,
    const unsigned short* __restrict__ Vt, unsigned short* __restrict__ O)
{
    __shared__ unsigned short K_lds[2][64 * 128];   // content[kk][c] = K[kv0+kk][c ^ ((kk&7)<<3)]
    __shared__ unsigned short Vt_lds[2][128 * 64];  // content[d][c]  = V[kv0 + (c ^ ((d&7)<<3))][d]
    __shared__ unsigned short P_lds[8][32 * 64];    // per-wave, key (row&7)<<3

    const int tid = threadIdx.x;
    const int w = tid >> 6;
    const int lane = tid & 63;
    const int lr = lane & 15;
    const int lg = lane >> 4;
    const int th = blockIdx.x;
    const int t = th >> 4;
    const int h = th & 15;
    const int p = blockIdx.y;
    const int qblk = (w < 4) ? (7 - p) : p;
    const int q0 = qblk * 128 + (w & 3) * 32;
    const int nkv = (7 - p) * 2 + 2;

    const unsigned short* Qh = Q + th * (E_ * D_);
    const unsigned short* Kh = K + th * (E_ * D_);
    const unsigned short* Vth = Vt + th * (D_ * E_);

    s16x8 qf[2][4];
#pragma unroll
    for (int mi = 0; mi < 2; ++mi)
#pragma unroll
        for (int kc = 0; kc < 4; ++kc)
            qf[mi][kc] = *reinterpret_cast<const s16x8*>(
                &Qh[(q0 + mi * 16 + lr) * D_ + kc * 32 + lg * 8]);

    f32x4 o[2][8];
    float mrow[2][4], lrow[2][4];
#pragma unroll
    for (int mi = 0; mi < 2; ++mi) {
#pragma unroll
        for (int n = 0; n < 8; ++n) o[mi][n] = f32x4{0.f, 0.f, 0.f, 0.f};
#pragma unroll
        for (int i = 0; i < 4; ++i) { mrow[mi][i] = -1e30f; lrow[mi][i] = 0.f; }
    }

    // prologue: stage tile 0 into buffer 0
#pragma unroll
    for (int it = 0; it < 2; ++it) {
        const int f = (it * 8 + w) * 64 + lane;
        const int kk = f >> 4, ck = (f & 15) * 8;
        gload_lds16(&Kh[kk * D_ + (ck ^ ((kk & 7) << 3))], &K_lds[0][f * 8]);
        const int dd = f >> 3, cv = (f & 7) * 8;
        gload_lds16(&Vth[dd * E_ + (cv ^ ((dd & 7) << 3))], &Vt_lds[0][f * 8]);
    }

    int cur = 0;
    for (int kb = 0; kb < nkv; ++kb) {
        const int kv0 = kb * 64;
        __syncthreads();  // drains prefetch vmcnt; releases buf[cur^1]

        if (kb + 1 < nkv) {  // issue next tile's loads (overlap with compute)
            const int kv1 = kv0 + 64;
#pragma unroll
            for (int it = 0; it < 2; ++it) {
                const int f = (it * 8 + w) * 64 + lane;
                const int kk = f >> 4, ck = (f & 15) * 8;
                gload_lds16(&Kh[(kv1 + kk) * D_ + (ck ^ ((kk & 7) << 3))],
                            &K_lds[cur ^ 1][f * 8]);
                const int dd = f >> 3, cv = (f & 7) * 8;
                gload_lds16(&Vth[dd * E_ + kv1 + (cv ^ ((dd & 7) << 3))],
                            &Vt_lds[cur ^ 1][f * 8]);
            }
        }

        if (kv0 <= q0 + 31) {
            const unsigned short* Kb = K_lds[cur];
            const unsigned short* Vb = Vt_lds[cur];

            // S = Q @ K^T  (32x64 per wave)
            f32x4 s[2][4];
            __builtin_amdgcn_s_setprio(1);
#pragma unroll
            for (int ni = 0; ni < 4; ++ni) {
                s16x8 kf[4];
#pragma unroll
                for (int kc = 0; kc < 4; ++kc)
                    kf[kc] = *reinterpret_cast<const s16x8*>(
                        &Kb[(ni * 16 + lr) * 128 + ((kc * 32 + lg * 8) ^ ((lr & 7) << 3))]);
#pragma unroll
                for (int mi = 0; mi < 2; ++mi) {
                    f32x4 a = f32x4{0.f, 0.f, 0.f, 0.f};
#pragma unroll
                    for (int kc = 0; kc < 4; ++kc) a = MFMA16(qf[mi][kc], kf[kc], a);
                    s[mi][ni] = a;
                }
            }
            __builtin_amdgcn_s_setprio(0);

            // causal mask (C/D: col=lane&15, row=(lane>>4)*4+i)
#pragma unroll
            for (int mi = 0; mi < 2; ++mi)
#pragma unroll
                for (int i = 0; i < 4; ++i) {
                    const int qrow = q0 + mi * 16 + lg * 4 + i;
#pragma unroll
                    for (int ni = 0; ni < 4; ++ni) {
                        const int kcol = kv0 + ni * 16 + lr;
                        if (kcol > qrow) s[mi][ni][i] = -1e30f;
                    }
                }
            // online softmax
#pragma unroll
            for (int mi = 0; mi < 2; ++mi)
#pragma unroll
                for (int i = 0; i < 4; ++i) {
                    float r = fmaxf(fmaxf(s[mi][0][i], s[mi][1][i]),
                                    fmaxf(s[mi][2][i], s[mi][3][i]));
                    r = fmaxf(r, __shfl_xor(r, 1));
                    r = fmaxf(r, __shfl_xor(r, 2));
                    r = fmaxf(r, __shfl_xor(r, 4));
                    r = fmaxf(r, __shfl_xor(r, 8));
                    const float mn = fmaxf(mrow[mi][i], r);
                    const float esc = __expf(mrow[mi][i] - mn);
                    mrow[mi][i] = mn;
                    float rs = 0.f;
#pragma unroll
                    for (int ni = 0; ni < 4; ++ni) {
                        const float pv = __expf(s[mi][ni][i] - mn);
                        s[mi][ni][i] = pv;
                        rs += pv;
                    }
                    rs += __shfl_xor(rs, 1);
                    rs += __shfl_xor(rs, 2);
                    rs += __shfl_xor(rs, 4);
                    rs += __shfl_xor(rs, 8);
                    lrow[mi][i] = lrow[mi][i] * esc + rs;
#pragma unroll
                    for (int n = 0; n < 8; ++n) o[mi][n][i] *= esc;
                }
            // P -> per-wave LDS (swizzled) to reach A-fragment layout
#pragma unroll
            for (int mi = 0; mi < 2; ++mi)
#pragma unroll
                for (int i = 0; i < 4; ++i) {
                    const int pr = mi * 16 + lg * 4 + i;
                    const int key = (pr & 7) << 3;
#pragma unroll
                    for (int ni = 0; ni < 4; ++ni)
                        P_lds[w][pr * 64 + ((ni * 16 + lr) ^ key)] = f2bf(s[mi][ni][i]);
                }
            // O += P @ V
            __builtin_amdgcn_s_setprio(1);
#pragma unroll
            for (int kc = 0; kc < 2; ++kc) {
                s16x8 pa[2];
#pragma unroll
                for (int mi = 0; mi < 2; ++mi)
                    pa[mi] = *reinterpret_cast<const s16x8*>(
                        &P_lds[w][(mi * 16 + lr) * 64 + ((kc * 32 + lg * 8) ^ ((lr & 7) << 3))]);
#pragma unroll
                for (int n = 0; n < 8; ++n) {
                    const int d = n * 16 + lr;
                    s16x8 vb = *reinterpret_cast<const s16x8*>(
                        &Vb[d * 64 + ((kc * 32 + lg * 8) ^ ((d & 7) << 3))]);
                    o[0][n] = MFMA16(pa[0], vb, o[0][n]);
                    o[1][n] = MFMA16(pa[1], vb, o[1][n]);
                }
            }
            __builtin_amdgcn_s_setprio(0);
        }
        cur ^= 1;
    }

    // epilogue: normalize and store attended [t][e][h*128+d]
    unsigned short* Ob = O + (size_t)t * E_ * C_ + h * D_;
#pragma unroll
    for (int mi = 0; mi < 2; ++mi) {
        float rcp[4];
#pragma unroll
        for (int i = 0; i < 4; ++i) rcp[i] = 1.0f / lrow[mi][i];
#pragma unroll
        for (int n = 0; n < 8; ++n)
#pragma unroll
            for (int i = 0; i < 4; ++i) {
                const int e = q0 + mi * 16 + lg * 4 + i;
                Ob[(size_t)e * C_ + n * 16 + lr] = f2bf(o[mi][n][i] * rcp[i]);
            }
    }
}

// ---------------- K3: output projection (M=4096, N=128, K=2048) ----------------
__global__ __launch_bounds__(256) void oproj_kernel(
    const unsigned short* __restrict__ A, const unsigned short* __restrict__ Wo16,
    const float* __restrict__ bo, float* __restrict__ out)
{
    const int tid = threadIdx.x;
    const int w = tid >> 6;
    const int lane = tid & 63;
    const int lr = lane & 15;
    const int lg = lane >> 4;
    const int mbase = blockIdx.x * 16;
    const int ncol = w * 32;

    f32x4 acc0 = f32x4{0.f, 0.f, 0.f, 0.f};
    f32x4 acc1 = f32x4{0.f, 0.f, 0.f, 0.f};
    const unsigned short* Arow = A + (size_t)(mbase + lr) * C_;
    const unsigned short* W0 = Wo16 + (size_t)(ncol + lr) * C_;
    const unsigned short* W1 = Wo16 + (size_t)(ncol + 16 + lr) * C_;

#pragma unroll 4
    for (int kb = 0; kb < 64; ++kb) {
        const int ko = kb * 32 + lg * 8;
        s16x8 af = *reinterpret_cast<const s16x8*>(Arow + ko);
        s16x8 b0 = *reinterpret_cast<const s16x8*>(W0 + ko);
        s16x8 b1 = *reinterpret_cast<const s16x8*>(W1 + ko);
        acc0 = MFMA16(af, b0, acc0);
        acc1 = MFMA16(af, b1, acc1);
    }

#pragma unroll
    for (int n = 0; n < 2; ++n) {
        const f32x4 acc = n ? acc1 : acc0;
        const int col = ncol + n * 16 + lr;
        const float bias = bo[col];
#pragma unroll
        for (int i = 0; i < 4; ++i)
            out[(mbase + lg * 4 + i) * D_ + col] = acc[i] + bias;
    }
}

extern "C" void kernel_launch(void* const* d_in, const int* in_sizes, int n_in,
                              void* d_out, int out_size, void* d_ws, size_t ws_size,
                              hipStream_t stream) {
    const float* key   = (const float*)d_in[0];
    const float* value = (const float*)d_in[1];
    const float* query = (const float*)d_in[2];
    const float* Wq = (const float*)d_in[3];
    const float* bq = (const float*)d_in[4];
    const float* Wk = (const float*)d_in[5];
    const float* bk = (const float*)d_in[6];
    const float* Wv = (const float*)d_in[7];
    const float* bv = (const float*)d_in[8];
    const float* Wo = (const float*)d_in[9];
    const float* bo = (const float*)d_in[10];
    float* out = (float*)d_out;

    unsigned short* ws = (unsigned short*)d_ws;
    const size_t QKV_ELEMS = (size_t)T_ * H_ * E_ * D_;  // 8388608
    unsigned short* q_ws = ws;
    unsigned short* k_ws = ws + QKV_ELEMS;
    unsigned short* v_ws = ws + 2 * QKV_ELEMS;            // V^T [T][H][D][E]
    unsigned short* att_ws = ws + 3 * QKV_ELEMS;
    unsigned short* wo16_ws = q_ws;                       // q_ws dead after attn

    // bf16 pre-conversions live in att region (dead until attn writes it)
    unsigned short* xq16 = att_ws;
    unsigned short* xk16 = att_ws + 524288;
    unsigned short* xv16 = att_ws + 2 * 524288;
    unsigned short* wq16 = att_ws + 3 * 524288;
    unsigned short* wk16 = wq16 + 262144;
    unsigned short* wv16 = wk16 + 262144;

    cvt_kernel<<<dim3(256), 256, 0, stream>>>(query, xq16);
    cvt_kernel<<<dim3(256), 256, 0, stream>>>(key,   xk16);
    cvt_kernel<<<dim3(256), 256, 0, stream>>>(value, xv16);
    cvt_kernel<<<dim3(128), 256, 0, stream>>>(Wq, wq16);
    cvt_kernel<<<dim3(128), 256, 0, stream>>>(Wk, wk16);
    cvt_kernel<<<dim3(128), 256, 0, stream>>>(Wv, wv16);

    qkv_kernel<<<dim3(32, 16, 3), 256, 0, stream>>>(xq16, xk16, xv16,
                                                    wq16, wk16, wv16,
                                                    bq, bk, bv,
                                                    q_ws, k_ws, v_ws);
    attn_kernel<<<dim3(64, 4), 512, 0, stream>>>(q_ws, k_ws, v_ws, att_ws);
    cvt_kernel<<<dim3(128), 256, 0, stream>>>(Wo, wo16_ws);
    oproj_kernel<<<dim3(256), 256, 0, stream>>>(att_ws, wo16_ws, bo, out);
}

// Round 6
// 124.550 us; speedup vs baseline: 2.4661x; 1.2443x over previous
//
#include <hip/hip_runtime.h>

#define T_ 4
#define E_ 1024
#define H_ 16
#define D_ 128
#define C_ 2048
#define QK_SCALE 0.08838834764831845f
#define LOG2E 1.4426950408889634f

typedef short s16x8 __attribute__((ext_vector_type(8)));
typedef short s16x4 __attribute__((ext_vector_type(4)));
typedef float f32x4 __attribute__((ext_vector_type(4)));

__device__ __forceinline__ unsigned short f2bf(float x) {
    unsigned u = __builtin_bit_cast(unsigned, x);
    u = (u + 0x7FFFu + ((u >> 16) & 1u)) >> 16;
    return (unsigned short)u;
}

__device__ __forceinline__ unsigned cvt_pk(float lo, float hi) {
    unsigned r;
    asm("v_cvt_pk_bf16_f32 %0, %1, %2" : "=v"(r) : "v"(lo), "v"(hi));
    return r;
}

#define MFMA16(a, b, c) __builtin_amdgcn_mfma_f32_16x16x32_bf16((a), (b), (c), 0, 0, 0)

__device__ __forceinline__ void gload_lds16(const unsigned short* g, unsigned short* l) {
    __builtin_amdgcn_global_load_lds(
        (const __attribute__((address_space(1))) unsigned int*)g,
        (__attribute__((address_space(3))) unsigned int*)l, 16, 0, 0);
}

// ---------------- generic f32 -> bf16 convert (2048 elems / block) ----------------
__global__ __launch_bounds__(256) void cvt_kernel(
    const float* __restrict__ src, unsigned short* __restrict__ dst)
{
    const int i = (blockIdx.x * 256 + threadIdx.x) * 8;
    float4 a = *reinterpret_cast<const float4*>(src + i);
    float4 b = *reinterpret_cast<const float4*>(src + i + 4);
    s16x8 r;
    r[0] = (short)f2bf(a.x); r[1] = (short)f2bf(a.y);
    r[2] = (short)f2bf(a.z); r[3] = (short)f2bf(a.w);
    r[4] = (short)f2bf(b.x); r[5] = (short)f2bf(b.y);
    r[6] = (short)f2bf(b.z); r[7] = (short)f2bf(b.w);
    *reinterpret_cast<s16x8*>(dst + i) = r;
}

// ---------------- fused 6-tensor f32 -> bf16 convert ----------------
__global__ __launch_bounds__(256) void cvt6_kernel(
    const float* __restrict__ q, const float* __restrict__ k, const float* __restrict__ v,
    const float* __restrict__ wq, const float* __restrict__ wk, const float* __restrict__ wv,
    unsigned short* __restrict__ base)
{
    const int b = blockIdx.x;
    const float* src;
    unsigned short* dst;
    int lb;
    if (b < 256)       { src = q;  dst = base;            lb = b; }
    else if (b < 512)  { src = k;  dst = base + 524288;   lb = b - 256; }
    else if (b < 768)  { src = v;  dst = base + 1048576;  lb = b - 512; }
    else if (b < 896)  { src = wq; dst = base + 1572864;  lb = b - 768; }
    else if (b < 1024) { src = wk; dst = base + 1835008;  lb = b - 896; }
    else               { src = wv; dst = base + 2097152;  lb = b - 1024; }
    const int i = (lb * 256 + threadIdx.x) * 8;
    float4 a = *reinterpret_cast<const float4*>(src + i);
    float4 c = *reinterpret_cast<const float4*>(src + i + 4);
    s16x8 r;
    r[0] = (short)f2bf(a.x); r[1] = (short)f2bf(a.y);
    r[2] = (short)f2bf(a.z); r[3] = (short)f2bf(a.w);
    r[4] = (short)f2bf(c.x); r[5] = (short)f2bf(c.y);
    r[6] = (short)f2bf(c.z); r[7] = (short)f2bf(c.w);
    *reinterpret_cast<s16x8*>(dst + i) = r;
}

// ---------------- K1: QKV projection (bf16 in, bf16 out) ----------------
// Q,K out: [T][H][E][128] with d stored at position delta(d)=n+8*lr (d=n*16+lr)
// (consistent permutation cancels inside QK^T). V out: physical-d TRANSPOSED
// [T][H][D][E]. Q pre-scaled by QK_SCALE*log2(e) for exp2-domain softmax.
__global__ __launch_bounds__(256) void qkv_kernel(
    const unsigned short* __restrict__ Xq, const unsigned short* __restrict__ Xk,
    const unsigned short* __restrict__ Xv,
    const unsigned short* __restrict__ Wq_, const unsigned short* __restrict__ Wk_,
    const unsigned short* __restrict__ Wv_,
    const float* __restrict__ bq_, const float* __restrict__ bk_, const float* __restrict__ bv_,
    unsigned short* __restrict__ oq, unsigned short* __restrict__ okk,
    unsigned short* __restrict__ ov)
{
    __shared__ unsigned short Tile[128 * 136];

    const int z = blockIdx.z;
    const unsigned short* X = (z == 0) ? Xq : (z == 1) ? Xk : Xv;
    const unsigned short* W = (z == 0) ? Wq_ : (z == 1) ? Wk_ : Wv_;
    const float* Bv = (z == 0) ? bq_ : (z == 1) ? bk_ : bv_;
    unsigned short* out = (z == 0) ? oq : (z == 1) ? okk : ov;
    const float scale = (z == 0) ? (QK_SCALE * LOG2E) : 1.0f;

    const int tid = threadIdx.x;
    const int w = tid >> 6;
    const int lane = tid & 63;
    const int lr = lane & 15;
    const int lg = lane >> 4;
    const int mbase = blockIdx.x * 128 + w * 32;
    const int nbase = blockIdx.y * 128;

    s16x8 af[2][4];
#pragma unroll
    for (int mi = 0; mi < 2; ++mi)
#pragma unroll
        for (int kc = 0; kc < 4; ++kc)
            af[mi][kc] = *reinterpret_cast<const s16x8*>(
                &X[(mbase + mi * 16 + lr) * D_ + kc * 32 + lg * 8]);

    f32x4 acc[2][8];
#pragma unroll
    for (int mi = 0; mi < 2; ++mi)
#pragma unroll
        for (int n = 0; n < 8; ++n) acc[mi][n] = f32x4{0.f, 0.f, 0.f, 0.f};

#pragma unroll
    for (int n = 0; n < 8; ++n) {
        s16x8 bf[4];
#pragma unroll
        for (int kc = 0; kc < 4; ++kc)
            bf[kc] = *reinterpret_cast<const s16x8*>(
                &W[(nbase + n * 16 + lr) * D_ + kc * 32 + lg * 8]);
#pragma unroll
        for (int mi = 0; mi < 2; ++mi)
#pragma unroll
            for (int kc = 0; kc < 4; ++kc)
                acc[mi][n] = MFMA16(af[mi][kc], bf[kc], acc[mi][n]);
    }

    float bias[8];
#pragma unroll
    for (int n = 0; n < 8; ++n) bias[n] = Bv[nbase + n * 16 + lr];

    if (z < 2) {
        // delta-permuted rows: position n + 8*lr -> b128 writes with cvt_pk
#pragma unroll
        for (int mi = 0; mi < 2; ++mi)
#pragma unroll
            for (int i = 0; i < 4; ++i) {
                const int rowl = w * 32 + mi * 16 + lg * 4 + i;
                float v0 = (acc[mi][0][i] + bias[0]) * scale;
                float v1 = (acc[mi][1][i] + bias[1]) * scale;
                float v2 = (acc[mi][2][i] + bias[2]) * scale;
                float v3 = (acc[mi][3][i] + bias[3]) * scale;
                float v4 = (acc[mi][4][i] + bias[4]) * scale;
                float v5 = (acc[mi][5][i] + bias[5]) * scale;
                float v6 = (acc[mi][6][i] + bias[6]) * scale;
                float v7 = (acc[mi][7][i] + bias[7]) * scale;
                union { s16x8 s; unsigned u[4]; } pk;
                pk.u[0] = cvt_pk(v0, v1);
                pk.u[1] = cvt_pk(v2, v3);
                pk.u[2] = cvt_pk(v4, v5);
                pk.u[3] = cvt_pk(v6, v7);
                *reinterpret_cast<s16x8*>(&Tile[rowl * 136 + 8 * lr]) = pk.s;
            }
    } else {
        // V: transpose to [d][e] within the tile (physical d)
#pragma unroll
        for (int n = 0; n < 8; ++n)
#pragma unroll
            for (int mi = 0; mi < 2; ++mi)
#pragma unroll
                for (int i = 0; i < 4; ++i) {
                    const int rowl = w * 32 + mi * 16 + lg * 4 + i;
                    Tile[(n * 16 + lr) * 136 + rowl] = f2bf(acc[mi][n][i] + bias[n]);
                }
    }
    __syncthreads();

    const int t = (blockIdx.x * 128) >> 10;
    const int e0 = (blockIdx.x * 128) & 1023;
    const int hh = blockIdx.y;
    const int r = tid >> 1;
    const int seg = tid & 1;
    if (z < 2) {
        unsigned short* dst = out + (((size_t)(t * H_ + hh) * E_ + e0) * D_)
                              + (size_t)r * D_ + seg * 64;
#pragma unroll
        for (int j = 0; j < 8; ++j)
            *reinterpret_cast<s16x8*>(dst + j * 8) =
                *reinterpret_cast<const s16x8*>(&Tile[r * 136 + seg * 64 + j * 8]);
    } else {
        unsigned short* dst = out + (((size_t)(t * H_ + hh) * D_ + r) * E_)
                              + e0 + seg * 64;
#pragma unroll
        for (int j = 0; j < 8; ++j)
            *reinterpret_cast<s16x8*>(dst + j * 8) =
                *reinterpret_cast<const s16x8*>(&Tile[r * 136 + seg * 64 + j * 8]);
    }
}

// ---------------- K2: causal flash attention (S^T formulation) ----------------
// grid (T*H, 4), 512 thr = 8 waves; waves 0-3 -> qblk 7-p, 4-7 -> qblk p.
// S^T = mfma(K,Q): lane holds P^T[kv][q]; PV = V^T @ P^T straight from registers
// (cvt_pk-packed B-frags, slot map matched on the V^T LDS reads). l via ones-MFMA.
__global__ __launch_bounds__(512, 2) void attn_kernel(
    const unsigned short* __restrict__ Q, const unsigned short* __restrict__ K,
    const unsigned short* __restrict__ Vt, unsigned short* __restrict__ O)
{
    __shared__ unsigned short K_lds[2][64 * 128];   // [kk][c] = K[kv0+kk][c ^ ((kk&7)<<3)]
    __shared__ unsigned short Vt_lds[2][128 * 64];  // [d][c]  = V[d][kv0 + (c ^ ((d&7)<<3))]

    const int tid = threadIdx.x;
    const int w = tid >> 6;
    const int lane = tid & 63;
    const int lr = lane & 15;
    const int g = lane >> 4;
    const int th = blockIdx.x;
    const int t = th >> 4;
    const int h = th & 15;
    const int p = blockIdx.y;
    const int qblk = (w < 4) ? (7 - p) : p;
    const int q0w = qblk * 128 + (w & 3) * 32;
    const int nkv = (7 - p) * 2 + 2;

    const unsigned short* Qh = Q + th * (E_ * D_);
    const unsigned short* Kh = K + th * (E_ * D_);
    const unsigned short* Vth = Vt + th * (D_ * E_);

    // Q as B-fragments (cols = q rows), pre-scaled in qkv
    s16x8 qb[2][4];
#pragma unroll
    for (int qi = 0; qi < 2; ++qi)
#pragma unroll
        for (int kc = 0; kc < 4; ++kc)
            qb[qi][kc] = *reinterpret_cast<const s16x8*>(
                &Qh[(q0w + qi * 16 + lr) * D_ + kc * 32 + g * 8]);

    s16x8 ones;
#pragma unroll
    for (int j = 0; j < 8; ++j) ones[j] = (short)0x3F80;

    f32x4 ot[8][2];
    f32x4 lac[2];
    float m[2];
#pragma unroll
    for (int dt = 0; dt < 8; ++dt)
#pragma unroll
        for (int qi = 0; qi < 2; ++qi) ot[dt][qi] = f32x4{0.f, 0.f, 0.f, 0.f};
    lac[0] = f32x4{0.f, 0.f, 0.f, 0.f};
    lac[1] = f32x4{0.f, 0.f, 0.f, 0.f};
    m[0] = -1e30f; m[1] = -1e30f;

    // prologue: stage tile 0
#pragma unroll
    for (int it = 0; it < 2; ++it) {
        const int f = (it * 8 + w) * 64 + lane;
        const int kk = f >> 4, ck = (f & 15) * 8;
        gload_lds16(&Kh[kk * D_ + (ck ^ ((kk & 7) << 3))], &K_lds[0][f * 8]);
        const int dd = f >> 3, cv = (f & 7) * 8;
        gload_lds16(&Vth[dd * E_ + (cv ^ ((dd & 7) << 3))], &Vt_lds[0][f * 8]);
    }

    int cur = 0;
    for (int kb = 0; kb < nkv; ++kb) {
        const int kv0 = kb * 64;
        __syncthreads();

        if (kb + 1 < nkv) {
            const int kv1 = kv0 + 64;
#pragma unroll
            for (int it = 0; it < 2; ++it) {
                const int f = (it * 8 + w) * 64 + lane;
                const int kk = f >> 4, ck = (f & 15) * 8;
                gload_lds16(&Kh[(kv1 + kk) * D_ + (ck ^ ((kk & 7) << 3))],
                            &K_lds[cur ^ 1][f * 8]);
                const int dd = f >> 3, cv = (f & 7) * 8;
                gload_lds16(&Vth[dd * E_ + kv1 + (cv ^ ((dd & 7) << 3))],
                            &Vt_lds[cur ^ 1][f * 8]);
            }
        }

        if (kv0 <= q0w + 31) {
            const unsigned short* Kb = K_lds[cur];
            const unsigned short* Vb = Vt_lds[cur];
            const int key = (lr & 7) << 3;

            // S^T[kv][q]: rows kv (4 tiles), cols q (2 tiles)
            f32x4 st[4][2];
            __builtin_amdgcn_s_setprio(1);
#pragma unroll
            for (int kvi = 0; kvi < 4; ++kvi) {
                s16x8 kf[4];
#pragma unroll
                for (int kc = 0; kc < 4; ++kc)
                    kf[kc] = *reinterpret_cast<const s16x8*>(
                        &Kb[(kvi * 16 + lr) * 128 + ((kc * 32 + g * 8) ^ key)]);
#pragma unroll
                for (int qi = 0; qi < 2; ++qi) {
                    f32x4 a = f32x4{0.f, 0.f, 0.f, 0.f};
#pragma unroll
                    for (int kc = 0; kc < 4; ++kc) a = MFMA16(kf[kc], qb[qi][kc], a);
                    st[kvi][qi] = a;
                }
            }
            __builtin_amdgcn_s_setprio(0);

            // causal mask: only diagonal tiles (wave-uniform branch)
            if (kv0 + 63 > q0w) {
#pragma unroll
                for (int kvi = 0; kvi < 4; ++kvi)
#pragma unroll
                    for (int i = 0; i < 4; ++i) {
                        const int kv = kv0 + kvi * 16 + g * 4 + i;
#pragma unroll
                        for (int qi = 0; qi < 2; ++qi) {
                            const int q = q0w + qi * 16 + lr;
                            if (kv > q) st[kvi][qi][i] = -1e30f;
                        }
                    }
            }

            // per-q-column max: lane-local over 16 vals, then xor-16/32
            float pm[2];
#pragma unroll
            for (int qi = 0; qi < 2; ++qi) {
                float a0 = fmaxf(fmaxf(st[0][qi][0], st[0][qi][1]),
                                 fmaxf(st[0][qi][2], st[0][qi][3]));
                float a1 = fmaxf(fmaxf(st[1][qi][0], st[1][qi][1]),
                                 fmaxf(st[1][qi][2], st[1][qi][3]));
                float a2 = fmaxf(fmaxf(st[2][qi][0], st[2][qi][1]),
                                 fmaxf(st[2][qi][2], st[2][qi][3]));
                float a3 = fmaxf(fmaxf(st[3][qi][0], st[3][qi][1]),
                                 fmaxf(st[3][qi][2], st[3][qi][3]));
                float r = fmaxf(fmaxf(a0, a1), fmaxf(a2, a3));
                r = fmaxf(r, __shfl_xor(r, 16));
                r = fmaxf(r, __shfl_xor(r, 32));
                pm[qi] = r;
            }

            // defer-max: rescale only when max grew past threshold
            const bool need = (pm[0] > m[0] + 8.f) || (pm[1] > m[1] + 8.f);
            if (__any(need)) {
#pragma unroll
                for (int qi = 0; qi < 2; ++qi) {
                    const float mn = fmaxf(m[qi], pm[qi]);
                    const float esc = exp2f(m[qi] - mn);
                    m[qi] = mn;
                    lac[qi] *= esc;
#pragma unroll
                    for (int dt = 0; dt < 8; ++dt) ot[dt][qi] *= esc;
                }
            }

            // P^T -> bf16 B-frags in registers (slot j: kv = 32kc+16(j>>2)+4g+(j&3))
            s16x8 pb[2][2];
#pragma unroll
            for (int kc = 0; kc < 2; ++kc)
#pragma unroll
                for (int qi = 0; qi < 2; ++qi) {
                    float e0 = exp2f(st[2 * kc][qi][0] - m[qi]);
                    float e1 = exp2f(st[2 * kc][qi][1] - m[qi]);
                    float e2 = exp2f(st[2 * kc][qi][2] - m[qi]);
                    float e3 = exp2f(st[2 * kc][qi][3] - m[qi]);
                    float f0 = exp2f(st[2 * kc + 1][qi][0] - m[qi]);
                    float f1 = exp2f(st[2 * kc + 1][qi][1] - m[qi]);
                    float f2 = exp2f(st[2 * kc + 1][qi][2] - m[qi]);
                    float f3 = exp2f(st[2 * kc + 1][qi][3] - m[qi]);
                    union { s16x8 s; unsigned u[4]; } pk;
                    pk.u[0] = cvt_pk(e0, e1);
                    pk.u[1] = cvt_pk(e2, e3);
                    pk.u[2] = cvt_pk(f0, f1);
                    pk.u[3] = cvt_pk(f2, f3);
                    pb[kc][qi] = pk.s;
                }

            // row-sum via ones-MFMA (l accumulates in C-layout, rows replicated)
#pragma unroll
            for (int kc = 0; kc < 2; ++kc) {
                lac[0] = MFMA16(ones, pb[kc][0], lac[0]);
                lac[1] = MFMA16(ones, pb[kc][1], lac[1]);
            }

            // O^T += V^T @ P^T  (A-frags: two b64 LDS reads, slot-matched)
            __builtin_amdgcn_s_setprio(1);
#pragma unroll
            for (int dt = 0; dt < 8; ++dt) {
                const int rb = (dt * 16 + lr) * 64;
#pragma unroll
                for (int kc = 0; kc < 2; ++kc) {
                    union { s16x8 v; s16x4 h[2]; } va;
                    va.h[0] = *reinterpret_cast<const s16x4*>(
                        &Vb[rb + ((kc * 32 + 4 * g) ^ key)]);
                    va.h[1] = *reinterpret_cast<const s16x4*>(
                        &Vb[rb + ((kc * 32 + 16 + 4 * g) ^ key)]);
                    ot[dt][0] = MFMA16(va.v, pb[kc][0], ot[dt][0]);
                    ot[dt][1] = MFMA16(va.v, pb[kc][1], ot[dt][1]);
                }
            }
            __builtin_amdgcn_s_setprio(0);
        }
        cur ^= 1;
    }

    // epilogue: O^T lane holds q=q0w+qi*16+lr, d=dt*16+g*4+i -> b64 stores
    unsigned short* Ob = O + (size_t)t * E_ * C_ + h * D_;
    const float rl0 = 1.0f / lac[0][0];
    const float rl1 = 1.0f / lac[1][0];
#pragma unroll
    for (int dt = 0; dt < 8; ++dt)
#pragma unroll
        for (int qi = 0; qi < 2; ++qi) {
            const float rl = qi ? rl1 : rl0;
            const int q = q0w + qi * 16 + lr;
            uint2 val;
            val.x = cvt_pk(ot[dt][qi][0] * rl, ot[dt][qi][1] * rl);
            val.y = cvt_pk(ot[dt][qi][2] * rl, ot[dt][qi][3] * rl);
            *reinterpret_cast<uint2*>(&Ob[(size_t)q * C_ + dt * 16 + 4 * g]) = val;
        }
}

// ---------------- K3: output projection (M=4096, N=128, K=2048) ----------------
__global__ __launch_bounds__(256) void oproj_kernel(
    const unsigned short* __restrict__ A, const unsigned short* __restrict__ Wo16,
    const float* __restrict__ bo, float* __restrict__ out)
{
    const int tid = threadIdx.x;
    const int w = tid >> 6;
    const int lane = tid & 63;
    const int lr = lane & 15;
    const int lg = lane >> 4;
    const int mbase = blockIdx.x * 16;
    const int ncol = w * 32;

    f32x4 acc0 = f32x4{0.f, 0.f, 0.f, 0.f};
    f32x4 acc1 = f32x4{0.f, 0.f, 0.f, 0.f};
    const unsigned short* Arow = A + (size_t)(mbase + lr) * C_;
    const unsigned short* W0 = Wo16 + (size_t)(ncol + lr) * C_;
    const unsigned short* W1 = Wo16 + (size_t)(ncol + 16 + lr) * C_;

#pragma unroll 4
    for (int kb = 0; kb < 64; ++kb) {
        const int ko = kb * 32 + lg * 8;
        s16x8 af = *reinterpret_cast<const s16x8*>(Arow + ko);
        s16x8 b0 = *reinterpret_cast<const s16x8*>(W0 + ko);
        s16x8 b1 = *reinterpret_cast<const s16x8*>(W1 + ko);
        acc0 = MFMA16(af, b0, acc0);
        acc1 = MFMA16(af, b1, acc1);
    }

#pragma unroll
    for (int n = 0; n < 2; ++n) {
        const f32x4 acc = n ? acc1 : acc0;
        const int col = ncol + n * 16 + lr;
        const float bias = bo[col];
#pragma unroll
        for (int i = 0; i < 4; ++i)
            out[(mbase + lg * 4 + i) * D_ + col] = acc[i] + bias;
    }
}

extern "C" void kernel_launch(void* const* d_in, const int* in_sizes, int n_in,
                              void* d_out, int out_size, void* d_ws, size_t ws_size,
                              hipStream_t stream) {
    const float* key   = (const float*)d_in[0];
    const float* value = (const float*)d_in[1];
    const float* query = (const float*)d_in[2];
    const float* Wq = (const float*)d_in[3];
    const float* bq = (const float*)d_in[4];
    const float* Wk = (const float*)d_in[5];
    const float* bk = (const float*)d_in[6];
    const float* Wv = (const float*)d_in[7];
    const float* bv = (const float*)d_in[8];
    const float* Wo = (const float*)d_in[9];
    const float* bo = (const float*)d_in[10];
    float* out = (float*)d_out;

    unsigned short* ws = (unsigned short*)d_ws;
    const size_t QKV_ELEMS = (size_t)T_ * H_ * E_ * D_;  // 8388608
    unsigned short* q_ws = ws;
    unsigned short* k_ws = ws + QKV_ELEMS;
    unsigned short* v_ws = ws + 2 * QKV_ELEMS;            // V^T [T][H][D][E]
    unsigned short* att_ws = ws + 3 * QKV_ELEMS;
    unsigned short* wo16_ws = q_ws;                       // q_ws dead after attn

    // bf16 staging lives in the att region (dead until attn writes it)
    unsigned short* xq16 = att_ws;
    unsigned short* xk16 = att_ws + 524288;
    unsigned short* xv16 = att_ws + 1048576;
    unsigned short* wq16 = att_ws + 1572864;
    unsigned short* wk16 = att_ws + 1835008;
    unsigned short* wv16 = att_ws + 2097152;

    cvt6_kernel<<<dim3(1152), 256, 0, stream>>>(query, key, value, Wq, Wk, Wv, att_ws);
    qkv_kernel<<<dim3(32, 16, 3), 256, 0, stream>>>(xq16, xk16, xv16,
                                                    wq16, wk16, wv16,
                                                    bq, bk, bv,
                                                    q_ws, k_ws, v_ws);
    attn_kernel<<<dim3(64, 4), 512, 0, stream>>>(q_ws, k_ws, v_ws, att_ws);
    cvt_kernel<<<dim3(128), 256, 0, stream>>>(Wo, wo16_ws);
    oproj_kernel<<<dim3(256), 256, 0, stream>>>(att_ws, wo16_ws, bo, out);
}

// Round 7
// 121.319 us; speedup vs baseline: 2.5318x; 1.0266x over previous
//
#include <hip/hip_runtime.h>

#define T_ 4
#define E_ 1024
#define H_ 16
#define D_ 128
#define C_ 2048
#define QK_SCALE 0.08838834764831845f
#define LOG2E 1.4426950408889634f

typedef short s16x8 __attribute__((ext_vector_type(8)));
typedef short s16x4 __attribute__((ext_vector_type(4)));
typedef float f32x4 __attribute__((ext_vector_type(4)));

__device__ __forceinline__ unsigned short f2bf(float x) {
    unsigned u = __builtin_bit_cast(unsigned, x);
    u = (u + 0x7FFFu + ((u >> 16) & 1u)) >> 16;
    return (unsigned short)u;
}

__device__ __forceinline__ unsigned cvt_pk(float lo, float hi) {
    unsigned r;
    asm("v_cvt_pk_bf16_f32 %0, %1, %2" : "=v"(r) : "v"(lo), "v"(hi));
    return r;
}

#define MFMA16(a, b, c) __builtin_amdgcn_mfma_f32_16x16x32_bf16((a), (b), (c), 0, 0, 0)

__device__ __forceinline__ void gload_lds16(const unsigned short* g, unsigned short* l) {
    __builtin_amdgcn_global_load_lds(
        (const __attribute__((address_space(1))) unsigned int*)g,
        (__attribute__((address_space(3))) unsigned int*)l, 16, 0, 0);
}

// ---------------- generic f32 -> bf16 convert (2048 elems / block) ----------------
__global__ __launch_bounds__(256) void cvt_kernel(
    const float* __restrict__ src, unsigned short* __restrict__ dst)
{
    const int i = (blockIdx.x * 256 + threadIdx.x) * 8;
    float4 a = *reinterpret_cast<const float4*>(src + i);
    float4 b = *reinterpret_cast<const float4*>(src + i + 4);
    s16x8 r;
    r[0] = (short)f2bf(a.x); r[1] = (short)f2bf(a.y);
    r[2] = (short)f2bf(a.z); r[3] = (short)f2bf(a.w);
    r[4] = (short)f2bf(b.x); r[5] = (short)f2bf(b.y);
    r[6] = (short)f2bf(b.z); r[7] = (short)f2bf(b.w);
    *reinterpret_cast<s16x8*>(dst + i) = r;
}

// ---------------- fused 6-tensor f32 -> bf16 convert ----------------
__global__ __launch_bounds__(256) void cvt6_kernel(
    const float* __restrict__ q, const float* __restrict__ k, const float* __restrict__ v,
    const float* __restrict__ wq, const float* __restrict__ wk, const float* __restrict__ wv,
    unsigned short* __restrict__ base)
{
    const int b = blockIdx.x;
    const float* src;
    unsigned short* dst;
    int lb;
    if (b < 256)       { src = q;  dst = base;            lb = b; }
    else if (b < 512)  { src = k;  dst = base + 524288;   lb = b - 256; }
    else if (b < 768)  { src = v;  dst = base + 1048576;  lb = b - 512; }
    else if (b < 896)  { src = wq; dst = base + 1572864;  lb = b - 768; }
    else if (b < 1024) { src = wk; dst = base + 1835008;  lb = b - 896; }
    else               { src = wv; dst = base + 2097152;  lb = b - 1024; }
    const int i = (lb * 256 + threadIdx.x) * 8;
    float4 a = *reinterpret_cast<const float4*>(src + i);
    float4 c = *reinterpret_cast<const float4*>(src + i + 4);
    s16x8 r;
    r[0] = (short)f2bf(a.x); r[1] = (short)f2bf(a.y);
    r[2] = (short)f2bf(a.z); r[3] = (short)f2bf(a.w);
    r[4] = (short)f2bf(c.x); r[5] = (short)f2bf(c.y);
    r[6] = (short)f2bf(c.z); r[7] = (short)f2bf(c.w);
    *reinterpret_cast<s16x8*>(dst + i) = r;
}

// ---------------- K1: QKV projection (bf16 in, bf16 out) ----------------
// Q,K out: [T][H][E][128] with d stored at position n+8*lr (d=n*16+lr).
// V out: TRANSPOSED [T][H][D][E] with e within-32 permuted:
//   e%32 = 16h+4g+i  stored at  pos%32 = 8g+4h+i   (makes attn PV A-frags
//   contiguous b128 in LDS). Q pre-scaled by QK_SCALE*log2(e).
__global__ __launch_bounds__(256) void qkv_kernel(
    const unsigned short* __restrict__ Xq, const unsigned short* __restrict__ Xk,
    const unsigned short* __restrict__ Xv,
    const unsigned short* __restrict__ Wq_, const unsigned short* __restrict__ Wk_,
    const unsigned short* __restrict__ Wv_,
    const float* __restrict__ bq_, const float* __restrict__ bk_, const float* __restrict__ bv_,
    unsigned short* __restrict__ oq, unsigned short* __restrict__ okk,
    unsigned short* __restrict__ ov)
{
    __shared__ unsigned short Tile[128 * 136];

    const int z = blockIdx.z;
    const unsigned short* X = (z == 0) ? Xq : (z == 1) ? Xk : Xv;
    const unsigned short* W = (z == 0) ? Wq_ : (z == 1) ? Wk_ : Wv_;
    const float* Bv = (z == 0) ? bq_ : (z == 1) ? bk_ : bv_;
    unsigned short* out = (z == 0) ? oq : (z == 1) ? okk : ov;
    const float scale = (z == 0) ? (QK_SCALE * LOG2E) : 1.0f;

    const int tid = threadIdx.x;
    const int w = tid >> 6;
    const int lane = tid & 63;
    const int lr = lane & 15;
    const int lg = lane >> 4;
    const int mbase = blockIdx.x * 128 + w * 32;
    const int nbase = blockIdx.y * 128;

    s16x8 af[2][4];
#pragma unroll
    for (int mi = 0; mi < 2; ++mi)
#pragma unroll
        for (int kc = 0; kc < 4; ++kc)
            af[mi][kc] = *reinterpret_cast<const s16x8*>(
                &X[(mbase + mi * 16 + lr) * D_ + kc * 32 + lg * 8]);

    f32x4 acc[2][8];
#pragma unroll
    for (int mi = 0; mi < 2; ++mi)
#pragma unroll
        for (int n = 0; n < 8; ++n) acc[mi][n] = f32x4{0.f, 0.f, 0.f, 0.f};

#pragma unroll
    for (int n = 0; n < 8; ++n) {
        s16x8 bf[4];
#pragma unroll
        for (int kc = 0; kc < 4; ++kc)
            bf[kc] = *reinterpret_cast<const s16x8*>(
                &W[(nbase + n * 16 + lr) * D_ + kc * 32 + lg * 8]);
#pragma unroll
        for (int mi = 0; mi < 2; ++mi)
#pragma unroll
            for (int kc = 0; kc < 4; ++kc)
                acc[mi][n] = MFMA16(af[mi][kc], bf[kc], acc[mi][n]);
    }

    float bias[8];
#pragma unroll
    for (int n = 0; n < 8; ++n) bias[n] = Bv[nbase + n * 16 + lr];

    if (z < 2) {
        // delta-permuted rows: position n + 8*lr -> b128 writes with cvt_pk
#pragma unroll
        for (int mi = 0; mi < 2; ++mi)
#pragma unroll
            for (int i = 0; i < 4; ++i) {
                const int rowl = w * 32 + mi * 16 + lg * 4 + i;
                float v0 = (acc[mi][0][i] + bias[0]) * scale;
                float v1 = (acc[mi][1][i] + bias[1]) * scale;
                float v2 = (acc[mi][2][i] + bias[2]) * scale;
                float v3 = (acc[mi][3][i] + bias[3]) * scale;
                float v4 = (acc[mi][4][i] + bias[4]) * scale;
                float v5 = (acc[mi][5][i] + bias[5]) * scale;
                float v6 = (acc[mi][6][i] + bias[6]) * scale;
                float v7 = (acc[mi][7][i] + bias[7]) * scale;
                union { s16x8 s; unsigned u[4]; } pk;
                pk.u[0] = cvt_pk(v0, v1);
                pk.u[1] = cvt_pk(v2, v3);
                pk.u[2] = cvt_pk(v4, v5);
                pk.u[3] = cvt_pk(v6, v7);
                *reinterpret_cast<s16x8*>(&Tile[rowl * 136 + 8 * lr]) = pk.s;
            }
    } else {
        // V: transpose to [d][e-pos], e within-32 permuted: pos = 8*lg+4*mi+i
#pragma unroll
        for (int n = 0; n < 8; ++n)
#pragma unroll
            for (int mi = 0; mi < 2; ++mi)
#pragma unroll
                for (int i = 0; i < 4; ++i) {
                    const int pos = w * 32 + 8 * lg + 4 * mi + i;
                    Tile[(n * 16 + lr) * 136 + pos] = f2bf(acc[mi][n][i] + bias[n]);
                }
    }
    __syncthreads();

    const int t = (blockIdx.x * 128) >> 10;
    const int e0 = (blockIdx.x * 128) & 1023;
    const int hh = blockIdx.y;
    const int r = tid >> 1;
    const int seg = tid & 1;
    if (z < 2) {
        unsigned short* dst = out + (((size_t)(t * H_ + hh) * E_ + e0) * D_)
                              + (size_t)r * D_ + seg * 64;
#pragma unroll
        for (int j = 0; j < 8; ++j)
            *reinterpret_cast<s16x8*>(dst + j * 8) =
                *reinterpret_cast<const s16x8*>(&Tile[r * 136 + seg * 64 + j * 8]);
    } else {
        unsigned short* dst = out + (((size_t)(t * H_ + hh) * D_ + r) * E_)
                              + e0 + seg * 64;
#pragma unroll
        for (int j = 0; j < 8; ++j)
            *reinterpret_cast<s16x8*>(dst + j * 8) =
                *reinterpret_cast<const s16x8*>(&Tile[r * 136 + seg * 64 + j * 8]);
    }
}

// ---------------- K2: causal flash attention (S^T formulation) ----------------
// grid (T*H, 8), 256 thr = 4 waves; block p -> qblk map [7,6,5,4,0,1,2,3]
// (co-resident pairs p/p+4 sum to equal work). 2 blocks/CU (64KB LDS each).
// PV A-frags are single b128 reads thanks to V's within-32 e-permutation.
__global__ __launch_bounds__(256, 2) void attn_kernel(
    const unsigned short* __restrict__ Q, const unsigned short* __restrict__ K,
    const unsigned short* __restrict__ Vt, unsigned short* __restrict__ O)
{
    __shared__ unsigned short K_lds[2][64 * 128];   // [kk][c] = K[kv0+kk][c ^ ((kk&7)<<3)]
    __shared__ unsigned short Vt_lds[2][128 * 64];  // [d][p]  = Vperm[d][kv0 + (p ^ ((d&7)<<3))]

    const int tid = threadIdx.x;
    const int w = tid >> 6;
    const int lane = tid & 63;
    const int lr = lane & 15;
    const int g = lane >> 4;
    const int th = blockIdx.x;
    const int t = th >> 4;
    const int h = th & 15;
    const int p = blockIdx.y;
    const int qblk = (p < 4) ? (7 - p) : (p - 4);
    const int q0w = qblk * 128 + w * 32;
    const int nkv = 2 * qblk + 2;

    const unsigned short* Qh = Q + th * (E_ * D_);
    const unsigned short* Kh = K + th * (E_ * D_);
    const unsigned short* Vth = Vt + th * (D_ * E_);

    // Q as B-fragments (cols = q rows), pre-scaled in qkv
    s16x8 qb[2][4];
#pragma unroll
    for (int qi = 0; qi < 2; ++qi)
#pragma unroll
        for (int kc = 0; kc < 4; ++kc)
            qb[qi][kc] = *reinterpret_cast<const s16x8*>(
                &Qh[(q0w + qi * 16 + lr) * D_ + kc * 32 + g * 8]);

    s16x8 ones;
#pragma unroll
    for (int j = 0; j < 8; ++j) ones[j] = (short)0x3F80;

    f32x4 ot[8][2];
    f32x4 lac[2];
    float m[2];
#pragma unroll
    for (int dt = 0; dt < 8; ++dt)
#pragma unroll
        for (int qi = 0; qi < 2; ++qi) ot[dt][qi] = f32x4{0.f, 0.f, 0.f, 0.f};
    lac[0] = f32x4{0.f, 0.f, 0.f, 0.f};
    lac[1] = f32x4{0.f, 0.f, 0.f, 0.f};
    m[0] = -1e30f; m[1] = -1e30f;

    // prologue: stage tile 0 (4 K-iters + 4 V-iters, 256 threads)
#pragma unroll
    for (int it = 0; it < 4; ++it) {
        const int f = it * 256 + tid;
        const int kk = f >> 4, ck = (f & 15) * 8;
        gload_lds16(&Kh[kk * D_ + (ck ^ ((kk & 7) << 3))], &K_lds[0][f * 8]);
        const int dd = f >> 3, cv = (f & 7) * 8;
        gload_lds16(&Vth[dd * E_ + (cv ^ ((dd & 7) << 3))], &Vt_lds[0][f * 8]);
    }

    int cur = 0;
    for (int kb = 0; kb < nkv; ++kb) {
        const int kv0 = kb * 64;
        __syncthreads();

        if (kb + 1 < nkv) {
            const int kv1 = kv0 + 64;
#pragma unroll
            for (int it = 0; it < 4; ++it) {
                const int f = it * 256 + tid;
                const int kk = f >> 4, ck = (f & 15) * 8;
                gload_lds16(&Kh[(kv1 + kk) * D_ + (ck ^ ((kk & 7) << 3))],
                            &K_lds[cur ^ 1][f * 8]);
                const int dd = f >> 3, cv = (f & 7) * 8;
                gload_lds16(&Vth[dd * E_ + kv1 + (cv ^ ((dd & 7) << 3))],
                            &Vt_lds[cur ^ 1][f * 8]);
            }
        }

        if (kv0 <= q0w + 31) {
            const unsigned short* Kb = K_lds[cur];
            const unsigned short* Vb = Vt_lds[cur];
            const int key = (lr & 7) << 3;

            // S^T[kv][q]: rows kv (4 tiles), cols q (2 tiles)
            f32x4 st[4][2];
            __builtin_amdgcn_s_setprio(1);
#pragma unroll
            for (int kvi = 0; kvi < 4; ++kvi) {
                s16x8 kf[4];
#pragma unroll
                for (int kc = 0; kc < 4; ++kc)
                    kf[kc] = *reinterpret_cast<const s16x8*>(
                        &Kb[(kvi * 16 + lr) * 128 + ((kc * 32 + g * 8) ^ key)]);
#pragma unroll
                for (int qi = 0; qi < 2; ++qi) {
                    f32x4 a = f32x4{0.f, 0.f, 0.f, 0.f};
#pragma unroll
                    for (int kc = 0; kc < 4; ++kc) a = MFMA16(kf[kc], qb[qi][kc], a);
                    st[kvi][qi] = a;
                }
            }
            __builtin_amdgcn_s_setprio(0);

            // causal mask: only diagonal tiles (wave-uniform branch)
            if (kv0 + 63 > q0w) {
#pragma unroll
                for (int kvi = 0; kvi < 4; ++kvi)
#pragma unroll
                    for (int i = 0; i < 4; ++i) {
                        const int kv = kv0 + kvi * 16 + g * 4 + i;
#pragma unroll
                        for (int qi = 0; qi < 2; ++qi) {
                            const int q = q0w + qi * 16 + lr;
                            if (kv > q) st[kvi][qi][i] = -1e30f;
                        }
                    }
            }

            // per-q-column max: lane-local over 16 vals, then xor-16/32
            float pm[2];
#pragma unroll
            for (int qi = 0; qi < 2; ++qi) {
                float a0 = fmaxf(fmaxf(st[0][qi][0], st[0][qi][1]),
                                 fmaxf(st[0][qi][2], st[0][qi][3]));
                float a1 = fmaxf(fmaxf(st[1][qi][0], st[1][qi][1]),
                                 fmaxf(st[1][qi][2], st[1][qi][3]));
                float a2 = fmaxf(fmaxf(st[2][qi][0], st[2][qi][1]),
                                 fmaxf(st[2][qi][2], st[2][qi][3]));
                float a3 = fmaxf(fmaxf(st[3][qi][0], st[3][qi][1]),
                                 fmaxf(st[3][qi][2], st[3][qi][3]));
                float r = fmaxf(fmaxf(a0, a1), fmaxf(a2, a3));
                r = fmaxf(r, __shfl_xor(r, 16));
                r = fmaxf(r, __shfl_xor(r, 32));
                pm[qi] = r;
            }

            // defer-max: rescale only when max grew past threshold
            const bool need = (pm[0] > m[0] + 8.f) || (pm[1] > m[1] + 8.f);
            if (__any(need)) {
#pragma unroll
                for (int qi = 0; qi < 2; ++qi) {
                    const float mn = fmaxf(m[qi], pm[qi]);
                    const float esc = exp2f(m[qi] - mn);
                    m[qi] = mn;
                    lac[qi] *= esc;
#pragma unroll
                    for (int dt = 0; dt < 8; ++dt) ot[dt][qi] *= esc;
                }
            }

            // P^T -> bf16 B-frags in registers (slot j: kv = 32kc+16(j>>2)+4g+(j&3))
            s16x8 pb[2][2];
#pragma unroll
            for (int kc = 0; kc < 2; ++kc)
#pragma unroll
                for (int qi = 0; qi < 2; ++qi) {
                    float e0 = exp2f(st[2 * kc][qi][0] - m[qi]);
                    float e1 = exp2f(st[2 * kc][qi][1] - m[qi]);
                    float e2 = exp2f(st[2 * kc][qi][2] - m[qi]);
                    float e3 = exp2f(st[2 * kc][qi][3] - m[qi]);
                    float f0 = exp2f(st[2 * kc + 1][qi][0] - m[qi]);
                    float f1 = exp2f(st[2 * kc + 1][qi][1] - m[qi]);
                    float f2 = exp2f(st[2 * kc + 1][qi][2] - m[qi]);
                    float f3 = exp2f(st[2 * kc + 1][qi][3] - m[qi]);
                    union { s16x8 s; unsigned u[4]; } pk;
                    pk.u[0] = cvt_pk(e0, e1);
                    pk.u[1] = cvt_pk(e2, e3);
                    pk.u[2] = cvt_pk(f0, f1);
                    pk.u[3] = cvt_pk(f2, f3);
                    pb[kc][qi] = pk.s;
                }

            // row-sum via ones-MFMA
#pragma unroll
            for (int kc = 0; kc < 2; ++kc) {
                lac[0] = MFMA16(ones, pb[kc][0], lac[0]);
                lac[1] = MFMA16(ones, pb[kc][1], lac[1]);
            }

            // O^T += V^T @ P^T  (A-frag: ONE b128 read, conflict-free)
            __builtin_amdgcn_s_setprio(1);
#pragma unroll
            for (int dt = 0; dt < 8; ++dt) {
                const int rb = (dt * 16 + lr) * 64;
#pragma unroll
                for (int kc = 0; kc < 2; ++kc) {
                    s16x8 va = *reinterpret_cast<const s16x8*>(
                        &Vb[rb + ((kc * 32 + 8 * g) ^ key)]);
                    ot[dt][0] = MFMA16(va, pb[kc][0], ot[dt][0]);
                    ot[dt][1] = MFMA16(va, pb[kc][1], ot[dt][1]);
                }
            }
            __builtin_amdgcn_s_setprio(0);
        }
        cur ^= 1;
    }

    // epilogue: O^T lane holds q=q0w+qi*16+lr, d=dt*16+g*4+i -> b64 stores
    unsigned short* Ob = O + (size_t)t * E_ * C_ + h * D_;
    const float rl0 = 1.0f / lac[0][0];
    const float rl1 = 1.0f / lac[1][0];
#pragma unroll
    for (int dt = 0; dt < 8; ++dt)
#pragma unroll
        for (int qi = 0; qi < 2; ++qi) {
            const float rl = qi ? rl1 : rl0;
            const int q = q0w + qi * 16 + lr;
            uint2 val;
            val.x = cvt_pk(ot[dt][qi][0] * rl, ot[dt][qi][1] * rl);
            val.y = cvt_pk(ot[dt][qi][2] * rl, ot[dt][qi][3] * rl);
            *reinterpret_cast<uint2*>(&Ob[(size_t)q * C_ + dt * 16 + 4 * g]) = val;
        }
}

// ---------------- K3: output projection (M=4096, N=128, K=2048) ----------------
// grid (256, 4): x = 16-row tile, y = K-quarter. Partial sums via atomicAdd
// into zeroed output; bias added by the y==0 segment only.
__global__ __launch_bounds__(256) void oproj_kernel(
    const unsigned short* __restrict__ A, const unsigned short* __restrict__ Wo16,
    const float* __restrict__ bo, float* __restrict__ out)
{
    const int tid = threadIdx.x;
    const int w = tid >> 6;
    const int lane = tid & 63;
    const int lr = lane & 15;
    const int lg = lane >> 4;
    const int mbase = blockIdx.x * 16;
    const int ncol = w * 32;
    const int k0 = blockIdx.y * 512;

    f32x4 acc0 = f32x4{0.f, 0.f, 0.f, 0.f};
    f32x4 acc1 = f32x4{0.f, 0.f, 0.f, 0.f};
    const unsigned short* Arow = A + (size_t)(mbase + lr) * C_ + k0;
    const unsigned short* W0 = Wo16 + (size_t)(ncol + lr) * C_ + k0;
    const unsigned short* W1 = Wo16 + (size_t)(ncol + 16 + lr) * C_ + k0;

#pragma unroll 4
    for (int kb = 0; kb < 16; ++kb) {
        const int ko = kb * 32 + lg * 8;
        s16x8 af = *reinterpret_cast<const s16x8*>(Arow + ko);
        s16x8 b0 = *reinterpret_cast<const s16x8*>(W0 + ko);
        s16x8 b1 = *reinterpret_cast<const s16x8*>(W1 + ko);
        acc0 = MFMA16(af, b0, acc0);
        acc1 = MFMA16(af, b1, acc1);
    }

#pragma unroll
    for (int n = 0; n < 2; ++n) {
        const f32x4 acc = n ? acc1 : acc0;
        const int col = ncol + n * 16 + lr;
        const float bias = (blockIdx.y == 0) ? bo[col] : 0.f;
#pragma unroll
        for (int i = 0; i < 4; ++i)
            atomicAdd(&out[(mbase + lg * 4 + i) * D_ + col], acc[i] + bias);
    }
}

extern "C" void kernel_launch(void* const* d_in, const int* in_sizes, int n_in,
                              void* d_out, int out_size, void* d_ws, size_t ws_size,
                              hipStream_t stream) {
    const float* key   = (const float*)d_in[0];
    const float* value = (const float*)d_in[1];
    const float* query = (const float*)d_in[2];
    const float* Wq = (const float*)d_in[3];
    const float* bq = (const float*)d_in[4];
    const float* Wk = (const float*)d_in[5];
    const float* bk = (const float*)d_in[6];
    const float* Wv = (const float*)d_in[7];
    const float* bv = (const float*)d_in[8];
    const float* Wo = (const float*)d_in[9];
    const float* bo = (const float*)d_in[10];
    float* out = (float*)d_out;

    unsigned short* ws = (unsigned short*)d_ws;
    const size_t QKV_ELEMS = (size_t)T_ * H_ * E_ * D_;  // 8388608
    unsigned short* q_ws = ws;
    unsigned short* k_ws = ws + QKV_ELEMS;
    unsigned short* v_ws = ws + 2 * QKV_ELEMS;            // V^T [T][H][D][E], e-permuted
    unsigned short* att_ws = ws + 3 * QKV_ELEMS;
    unsigned short* wo16_ws = q_ws;                       // q_ws dead after attn

    // bf16 staging lives in the att region (dead until attn writes it)
    unsigned short* xq16 = att_ws;
    unsigned short* xk16 = att_ws + 524288;
    unsigned short* xv16 = att_ws + 1048576;
    unsigned short* wq16 = att_ws + 1572864;
    unsigned short* wk16 = att_ws + 1835008;
    unsigned short* wv16 = att_ws + 2097152;

    cvt6_kernel<<<dim3(1152), 256, 0, stream>>>(query, key, value, Wq, Wk, Wv, att_ws);
    qkv_kernel<<<dim3(32, 16, 3), 256, 0, stream>>>(xq16, xk16, xv16,
                                                    wq16, wk16, wv16,
                                                    bq, bk, bv,
                                                    q_ws, k_ws, v_ws);
    attn_kernel<<<dim3(64, 8), 256, 0, stream>>>(q_ws, k_ws, v_ws, att_ws);
    cvt_kernel<<<dim3(128), 256, 0, stream>>>(Wo, wo16_ws);
    hipMemsetAsync(out, 0, (size_t)out_size * sizeof(float), stream);
    oproj_kernel<<<dim3(256, 4), 256, 0, stream>>>(att_ws, wo16_ws, bo, out);
}

// Round 8
// 111.306 us; speedup vs baseline: 2.7595x; 1.0900x over previous
//
#include <hip/hip_runtime.h>

#define T_ 4
#define E_ 1024
#define H_ 16
#define D_ 128
#define C_ 2048
#define QK_SCALE 0.08838834764831845f
#define LOG2E 1.4426950408889634f

typedef short s16x8 __attribute__((ext_vector_type(8)));
typedef short s16x4 __attribute__((ext_vector_type(4)));
typedef float f32x4 __attribute__((ext_vector_type(4)));

__device__ __forceinline__ unsigned short f2bf(float x) {
    unsigned u = __builtin_bit_cast(unsigned, x);
    u = (u + 0x7FFFu + ((u >> 16) & 1u)) >> 16;
    return (unsigned short)u;
}

__device__ __forceinline__ unsigned cvt_pk(float lo, float hi) {
    unsigned r;
    asm("v_cvt_pk_bf16_f32 %0, %1, %2" : "=v"(r) : "v"(lo), "v"(hi));
    return r;
}

#define MFMA16(a, b, c) __builtin_amdgcn_mfma_f32_16x16x32_bf16((a), (b), (c), 0, 0, 0)

__device__ __forceinline__ void gload_lds16(const unsigned short* g, unsigned short* l) {
    __builtin_amdgcn_global_load_lds(
        (const __attribute__((address_space(1))) unsigned int*)g,
        (__attribute__((address_space(3))) unsigned int*)l, 16, 0, 0);
}

// ---------------- generic f32 -> bf16 convert (2048 elems / block) ----------------
__global__ __launch_bounds__(256) void cvt_kernel(
    const float* __restrict__ src, unsigned short* __restrict__ dst)
{
    const int i = (blockIdx.x * 256 + threadIdx.x) * 8;
    float4 a = *reinterpret_cast<const float4*>(src + i);
    float4 b = *reinterpret_cast<const float4*>(src + i + 4);
    s16x8 r;
    r[0] = (short)f2bf(a.x); r[1] = (short)f2bf(a.y);
    r[2] = (short)f2bf(a.z); r[3] = (short)f2bf(a.w);
    r[4] = (short)f2bf(b.x); r[5] = (short)f2bf(b.y);
    r[6] = (short)f2bf(b.z); r[7] = (short)f2bf(b.w);
    *reinterpret_cast<s16x8*>(dst + i) = r;
}

// ---------------- fused 6-tensor f32 -> bf16 convert ----------------
__global__ __launch_bounds__(256) void cvt6_kernel(
    const float* __restrict__ q, const float* __restrict__ k, const float* __restrict__ v,
    const float* __restrict__ wq, const float* __restrict__ wk, const float* __restrict__ wv,
    unsigned short* __restrict__ base)
{
    const int b = blockIdx.x;
    const float* src;
    unsigned short* dst;
    int lb;
    if (b < 256)       { src = q;  dst = base;            lb = b; }
    else if (b < 512)  { src = k;  dst = base + 524288;   lb = b - 256; }
    else if (b < 768)  { src = v;  dst = base + 1048576;  lb = b - 512; }
    else if (b < 896)  { src = wq; dst = base + 1572864;  lb = b - 768; }
    else if (b < 1024) { src = wk; dst = base + 1835008;  lb = b - 896; }
    else               { src = wv; dst = base + 2097152;  lb = b - 1024; }
    const int i = (lb * 256 + threadIdx.x) * 8;
    float4 a = *reinterpret_cast<const float4*>(src + i);
    float4 c = *reinterpret_cast<const float4*>(src + i + 4);
    s16x8 r;
    r[0] = (short)f2bf(a.x); r[1] = (short)f2bf(a.y);
    r[2] = (short)f2bf(a.z); r[3] = (short)f2bf(a.w);
    r[4] = (short)f2bf(c.x); r[5] = (short)f2bf(c.y);
    r[6] = (short)f2bf(c.z); r[7] = (short)f2bf(c.w);
    *reinterpret_cast<s16x8*>(dst + i) = r;
}

// ---------------- K1: QKV projection (bf16 in, bf16 out) ----------------
// Q,K out: [T][H][E][128] with d stored at position n+8*lr (d=n*16+lr).
// V out: TRANSPOSED [T][H][D][E] with e within-32 permuted:
//   e%32 = 16h+4g+i  stored at  pos%32 = 8g+4h+i.
// Q pre-scaled by QK_SCALE*log2(e).
// Epilogue: LDS restage + WAVE-CONTIGUOUS stores (4 full rows / instr).
__global__ __launch_bounds__(256) void qkv_kernel(
    const unsigned short* __restrict__ Xq, const unsigned short* __restrict__ Xk,
    const unsigned short* __restrict__ Xv,
    const unsigned short* __restrict__ Wq_, const unsigned short* __restrict__ Wk_,
    const unsigned short* __restrict__ Wv_,
    const float* __restrict__ bq_, const float* __restrict__ bk_, const float* __restrict__ bv_,
    unsigned short* __restrict__ oq, unsigned short* __restrict__ okk,
    unsigned short* __restrict__ ov)
{
    __shared__ unsigned short Tile[128 * 136];

    const int z = blockIdx.z;
    const unsigned short* X = (z == 0) ? Xq : (z == 1) ? Xk : Xv;
    const unsigned short* W = (z == 0) ? Wq_ : (z == 1) ? Wk_ : Wv_;
    const float* Bv = (z == 0) ? bq_ : (z == 1) ? bk_ : bv_;
    unsigned short* out = (z == 0) ? oq : (z == 1) ? okk : ov;
    const float scale = (z == 0) ? (QK_SCALE * LOG2E) : 1.0f;

    const int tid = threadIdx.x;
    const int w = tid >> 6;
    const int lane = tid & 63;
    const int lr = lane & 15;
    const int lg = lane >> 4;
    const int mbase = blockIdx.x * 128 + w * 32;
    const int nbase = blockIdx.y * 128;

    s16x8 af[2][4];
#pragma unroll
    for (int mi = 0; mi < 2; ++mi)
#pragma unroll
        for (int kc = 0; kc < 4; ++kc)
            af[mi][kc] = *reinterpret_cast<const s16x8*>(
                &X[(mbase + mi * 16 + lr) * D_ + kc * 32 + lg * 8]);

    f32x4 acc[2][8];
#pragma unroll
    for (int mi = 0; mi < 2; ++mi)
#pragma unroll
        for (int n = 0; n < 8; ++n) acc[mi][n] = f32x4{0.f, 0.f, 0.f, 0.f};

#pragma unroll
    for (int n = 0; n < 8; ++n) {
        s16x8 bf[4];
#pragma unroll
        for (int kc = 0; kc < 4; ++kc)
            bf[kc] = *reinterpret_cast<const s16x8*>(
                &W[(nbase + n * 16 + lr) * D_ + kc * 32 + lg * 8]);
#pragma unroll
        for (int mi = 0; mi < 2; ++mi)
#pragma unroll
            for (int kc = 0; kc < 4; ++kc)
                acc[mi][n] = MFMA16(af[mi][kc], bf[kc], acc[mi][n]);
    }

    float bias[8];
#pragma unroll
    for (int n = 0; n < 8; ++n) bias[n] = Bv[nbase + n * 16 + lr];

    if (z < 2) {
        // delta-permuted rows: position n + 8*lr -> b128 writes with cvt_pk
#pragma unroll
        for (int mi = 0; mi < 2; ++mi)
#pragma unroll
            for (int i = 0; i < 4; ++i) {
                const int rowl = w * 32 + mi * 16 + lg * 4 + i;
                float v0 = (acc[mi][0][i] + bias[0]) * scale;
                float v1 = (acc[mi][1][i] + bias[1]) * scale;
                float v2 = (acc[mi][2][i] + bias[2]) * scale;
                float v3 = (acc[mi][3][i] + bias[3]) * scale;
                float v4 = (acc[mi][4][i] + bias[4]) * scale;
                float v5 = (acc[mi][5][i] + bias[5]) * scale;
                float v6 = (acc[mi][6][i] + bias[6]) * scale;
                float v7 = (acc[mi][7][i] + bias[7]) * scale;
                union { s16x8 s; unsigned u[4]; } pk;
                pk.u[0] = cvt_pk(v0, v1);
                pk.u[1] = cvt_pk(v2, v3);
                pk.u[2] = cvt_pk(v4, v5);
                pk.u[3] = cvt_pk(v6, v7);
                *reinterpret_cast<s16x8*>(&Tile[rowl * 136 + 8 * lr]) = pk.s;
            }
    } else {
        // V: transpose to [d][e-pos]; lane's 8 values (mi,i) are contiguous
        // at pos = w*32 + 8*lg + 4*mi + i  -> one b128 write per n
#pragma unroll
        for (int n = 0; n < 8; ++n) {
            union { s16x8 s; unsigned u[4]; } pk;
            pk.u[0] = cvt_pk(acc[0][n][0] + bias[n], acc[0][n][1] + bias[n]);
            pk.u[1] = cvt_pk(acc[0][n][2] + bias[n], acc[0][n][3] + bias[n]);
            pk.u[2] = cvt_pk(acc[1][n][0] + bias[n], acc[1][n][1] + bias[n]);
            pk.u[3] = cvt_pk(acc[1][n][2] + bias[n], acc[1][n][3] + bias[n]);
            *reinterpret_cast<s16x8*>(&Tile[(n * 16 + lr) * 136 + w * 32 + 8 * lg]) = pk.s;
        }
    }
    __syncthreads();

    // write-out: per instruction each wave stores 4 complete rows
    // (Q/K: 1KB contiguous; V: 4 x 256B segments)
    const int t = (blockIdx.x * 128) >> 10;
    const int e0 = (blockIdx.x * 128) & 1023;
    const int hh = blockIdx.y;
    const int row16 = tid >> 4;       // 0..15
    const int c8 = (tid & 15) * 8;    // column offset (elements)
    if (z < 2) {
        unsigned short* dst = out + (((size_t)(t * H_ + hh) * E_ + e0) * D_);
#pragma unroll
        for (int j = 0; j < 8; ++j) {
            const int row = j * 16 + row16;
            *reinterpret_cast<s16x8*>(dst + (size_t)row * D_ + c8) =
                *reinterpret_cast<const s16x8*>(&Tile[row * 136 + c8]);
        }
    } else {
        unsigned short* dst = out + ((size_t)(t * H_ + hh) * D_) * E_ + e0;
#pragma unroll
        for (int j = 0; j < 8; ++j) {
            const int row = j * 16 + row16;
            *reinterpret_cast<s16x8*>(dst + (size_t)row * E_ + c8) =
                *reinterpret_cast<const s16x8*>(&Tile[row * 136 + c8]);
        }
    }
}

// ---------------- K2: causal flash attention (S^T formulation) ----------------
// grid (T*H, 8), 256 thr = 4 waves; block p -> qblk map [7,6,5,4,0,1,2,3]
// (co-resident pairs p/p+4 sum to equal work). 2 blocks/CU (64KB LDS each).
// PV A-frags are single b128 reads thanks to V's within-32 e-permutation.
__global__ __launch_bounds__(256, 2) void attn_kernel(
    const unsigned short* __restrict__ Q, const unsigned short* __restrict__ K,
    const unsigned short* __restrict__ Vt, unsigned short* __restrict__ O)
{
    __shared__ unsigned short K_lds[2][64 * 128];   // [kk][c] = K[kv0+kk][c ^ ((kk&7)<<3)]
    __shared__ unsigned short Vt_lds[2][128 * 64];  // [d][p]  = Vperm[d][kv0 + (p ^ ((d&7)<<3))]

    const int tid = threadIdx.x;
    const int w = tid >> 6;
    const int lane = tid & 63;
    const int lr = lane & 15;
    const int g = lane >> 4;
    const int th = blockIdx.x;
    const int t = th >> 4;
    const int h = th & 15;
    const int p = blockIdx.y;
    const int qblk = (p < 4) ? (7 - p) : (p - 4);
    const int q0w = qblk * 128 + w * 32;
    const int nkv = 2 * qblk + 2;

    const unsigned short* Qh = Q + th * (E_ * D_);
    const unsigned short* Kh = K + th * (E_ * D_);
    const unsigned short* Vth = Vt + th * (D_ * E_);

    // Q as B-fragments (cols = q rows), pre-scaled in qkv
    s16x8 qb[2][4];
#pragma unroll
    for (int qi = 0; qi < 2; ++qi)
#pragma unroll
        for (int kc = 0; kc < 4; ++kc)
            qb[qi][kc] = *reinterpret_cast<const s16x8*>(
                &Qh[(q0w + qi * 16 + lr) * D_ + kc * 32 + g * 8]);

    s16x8 ones;
#pragma unroll
    for (int j = 0; j < 8; ++j) ones[j] = (short)0x3F80;

    f32x4 ot[8][2];
    f32x4 lac[2];
    float m[2];
#pragma unroll
    for (int dt = 0; dt < 8; ++dt)
#pragma unroll
        for (int qi = 0; qi < 2; ++qi) ot[dt][qi] = f32x4{0.f, 0.f, 0.f, 0.f};
    lac[0] = f32x4{0.f, 0.f, 0.f, 0.f};
    lac[1] = f32x4{0.f, 0.f, 0.f, 0.f};
    m[0] = -1e30f; m[1] = -1e30f;

    // prologue: stage tile 0 (4 K-iters + 4 V-iters, 256 threads)
#pragma unroll
    for (int it = 0; it < 4; ++it) {
        const int f = it * 256 + tid;
        const int kk = f >> 4, ck = (f & 15) * 8;
        gload_lds16(&Kh[kk * D_ + (ck ^ ((kk & 7) << 3))], &K_lds[0][f * 8]);
        const int dd = f >> 3, cv = (f & 7) * 8;
        gload_lds16(&Vth[dd * E_ + (cv ^ ((dd & 7) << 3))], &Vt_lds[0][f * 8]);
    }

    int cur = 0;
    for (int kb = 0; kb < nkv; ++kb) {
        const int kv0 = kb * 64;
        __syncthreads();

        if (kb + 1 < nkv) {
            const int kv1 = kv0 + 64;
#pragma unroll
            for (int it = 0; it < 4; ++it) {
                const int f = it * 256 + tid;
                const int kk = f >> 4, ck = (f & 15) * 8;
                gload_lds16(&Kh[(kv1 + kk) * D_ + (ck ^ ((kk & 7) << 3))],
                            &K_lds[cur ^ 1][f * 8]);
                const int dd = f >> 3, cv = (f & 7) * 8;
                gload_lds16(&Vth[dd * E_ + kv1 + (cv ^ ((dd & 7) << 3))],
                            &Vt_lds[cur ^ 1][f * 8]);
            }
        }

        if (kv0 <= q0w + 31) {
            const unsigned short* Kb = K_lds[cur];
            const unsigned short* Vb = Vt_lds[cur];
            const int key = (lr & 7) << 3;

            // S^T[kv][q]: rows kv (4 tiles), cols q (2 tiles)
            f32x4 st[4][2];
            __builtin_amdgcn_s_setprio(1);
#pragma unroll
            for (int kvi = 0; kvi < 4; ++kvi) {
                s16x8 kf[4];
#pragma unroll
                for (int kc = 0; kc < 4; ++kc)
                    kf[kc] = *reinterpret_cast<const s16x8*>(
                        &Kb[(kvi * 16 + lr) * 128 + ((kc * 32 + g * 8) ^ key)]);
#pragma unroll
                for (int qi = 0; qi < 2; ++qi) {
                    f32x4 a = f32x4{0.f, 0.f, 0.f, 0.f};
#pragma unroll
                    for (int kc = 0; kc < 4; ++kc) a = MFMA16(kf[kc], qb[qi][kc], a);
                    st[kvi][qi] = a;
                }
            }
            __builtin_amdgcn_s_setprio(0);

            // causal mask: only diagonal tiles (wave-uniform branch)
            if (kv0 + 63 > q0w) {
#pragma unroll
                for (int kvi = 0; kvi < 4; ++kvi)
#pragma unroll
                    for (int i = 0; i < 4; ++i) {
                        const int kv = kv0 + kvi * 16 + g * 4 + i;
#pragma unroll
                        for (int qi = 0; qi < 2; ++qi) {
                            const int q = q0w + qi * 16 + lr;
                            if (kv > q) st[kvi][qi][i] = -1e30f;
                        }
                    }
            }

            // per-q-column max: lane-local over 16 vals, then xor-16/32
            float pm[2];
#pragma unroll
            for (int qi = 0; qi < 2; ++qi) {
                float a0 = fmaxf(fmaxf(st[0][qi][0], st[0][qi][1]),
                                 fmaxf(st[0][qi][2], st[0][qi][3]));
                float a1 = fmaxf(fmaxf(st[1][qi][0], st[1][qi][1]),
                                 fmaxf(st[1][qi][2], st[1][qi][3]));
                float a2 = fmaxf(fmaxf(st[2][qi][0], st[2][qi][1]),
                                 fmaxf(st[2][qi][2], st[2][qi][3]));
                float a3 = fmaxf(fmaxf(st[3][qi][0], st[3][qi][1]),
                                 fmaxf(st[3][qi][2], st[3][qi][3]));
                float r = fmaxf(fmaxf(a0, a1), fmaxf(a2, a3));
                r = fmaxf(r, __shfl_xor(r, 16));
                r = fmaxf(r, __shfl_xor(r, 32));
                pm[qi] = r;
            }

            // defer-max: rescale only when max grew past threshold
            const bool need = (pm[0] > m[0] + 8.f) || (pm[1] > m[1] + 8.f);
            if (__any(need)) {
#pragma unroll
                for (int qi = 0; qi < 2; ++qi) {
                    const float mn = fmaxf(m[qi], pm[qi]);
                    const float esc = exp2f(m[qi] - mn);
                    m[qi] = mn;
                    lac[qi] *= esc;
#pragma unroll
                    for (int dt = 0; dt < 8; ++dt) ot[dt][qi] *= esc;
                }
            }

            // P^T -> bf16 B-frags in registers (slot j: kv = 32kc+16(j>>2)+4g+(j&3))
            s16x8 pb[2][2];
#pragma unroll
            for (int kc = 0; kc < 2; ++kc)
#pragma unroll
                for (int qi = 0; qi < 2; ++qi) {
                    float e0 = exp2f(st[2 * kc][qi][0] - m[qi]);
                    float e1 = exp2f(st[2 * kc][qi][1] - m[qi]);
                    float e2 = exp2f(st[2 * kc][qi][2] - m[qi]);
                    float e3 = exp2f(st[2 * kc][qi][3] - m[qi]);
                    float f0 = exp2f(st[2 * kc + 1][qi][0] - m[qi]);
                    float f1 = exp2f(st[2 * kc + 1][qi][1] - m[qi]);
                    float f2 = exp2f(st[2 * kc + 1][qi][2] - m[qi]);
                    float f3 = exp2f(st[2 * kc + 1][qi][3] - m[qi]);
                    union { s16x8 s; unsigned u[4]; } pk;
                    pk.u[0] = cvt_pk(e0, e1);
                    pk.u[1] = cvt_pk(e2, e3);
                    pk.u[2] = cvt_pk(f0, f1);
                    pk.u[3] = cvt_pk(f2, f3);
                    pb[kc][qi] = pk.s;
                }

            // row-sum via ones-MFMA
#pragma unroll
            for (int kc = 0; kc < 2; ++kc) {
                lac[0] = MFMA16(ones, pb[kc][0], lac[0]);
                lac[1] = MFMA16(ones, pb[kc][1], lac[1]);
            }

            // O^T += V^T @ P^T  (A-frag: ONE b128 read, conflict-free)
            __builtin_amdgcn_s_setprio(1);
#pragma unroll
            for (int dt = 0; dt < 8; ++dt) {
                const int rb = (dt * 16 + lr) * 64;
#pragma unroll
                for (int kc = 0; kc < 2; ++kc) {
                    s16x8 va = *reinterpret_cast<const s16x8*>(
                        &Vb[rb + ((kc * 32 + 8 * g) ^ key)]);
                    ot[dt][0] = MFMA16(va, pb[kc][0], ot[dt][0]);
                    ot[dt][1] = MFMA16(va, pb[kc][1], ot[dt][1]);
                }
            }
            __builtin_amdgcn_s_setprio(0);
        }
        cur ^= 1;
    }

    // epilogue: O^T lane holds q=q0w+qi*16+lr, d=dt*16+g*4+i -> b64 stores
    unsigned short* Ob = O + (size_t)t * E_ * C_ + h * D_;
    const float rl0 = 1.0f / lac[0][0];
    const float rl1 = 1.0f / lac[1][0];
#pragma unroll
    for (int dt = 0; dt < 8; ++dt)
#pragma unroll
        for (int qi = 0; qi < 2; ++qi) {
            const float rl = qi ? rl1 : rl0;
            const int q = q0w + qi * 16 + lr;
            uint2 val;
            val.x = cvt_pk(ot[dt][qi][0] * rl, ot[dt][qi][1] * rl);
            val.y = cvt_pk(ot[dt][qi][2] * rl, ot[dt][qi][3] * rl);
            *reinterpret_cast<uint2*>(&Ob[(size_t)q * C_ + dt * 16 + 4 * g]) = val;
        }
}

// ---------------- K3: output projection (M=4096, N=128, K=2048) ----------------
// grid (256, 4): x = 16-row tile, y = K-quarter. Partial sums via atomicAdd
// into zeroed output; bias added by the y==0 segment only.
__global__ __launch_bounds__(256) void oproj_kernel(
    const unsigned short* __restrict__ A, const unsigned short* __restrict__ Wo16,
    const float* __restrict__ bo, float* __restrict__ out)
{
    const int tid = threadIdx.x;
    const int w = tid >> 6;
    const int lane = tid & 63;
    const int lr = lane & 15;
    const int lg = lane >> 4;
    const int mbase = blockIdx.x * 16;
    const int ncol = w * 32;
    const int k0 = blockIdx.y * 512;

    f32x4 acc0 = f32x4{0.f, 0.f, 0.f, 0.f};
    f32x4 acc1 = f32x4{0.f, 0.f, 0.f, 0.f};
    const unsigned short* Arow = A + (size_t)(mbase + lr) * C_ + k0;
    const unsigned short* W0 = Wo16 + (size_t)(ncol + lr) * C_ + k0;
    const unsigned short* W1 = Wo16 + (size_t)(ncol + 16 + lr) * C_ + k0;

#pragma unroll 4
    for (int kb = 0; kb < 16; ++kb) {
        const int ko = kb * 32 + lg * 8;
        s16x8 af = *reinterpret_cast<const s16x8*>(Arow + ko);
        s16x8 b0 = *reinterpret_cast<const s16x8*>(W0 + ko);
        s16x8 b1 = *reinterpret_cast<const s16x8*>(W1 + ko);
        acc0 = MFMA16(af, b0, acc0);
        acc1 = MFMA16(af, b1, acc1);
    }

#pragma unroll
    for (int n = 0; n < 2; ++n) {
        const f32x4 acc = n ? acc1 : acc0;
        const int col = ncol + n * 16 + lr;
        const float bias = (blockIdx.y == 0) ? bo[col] : 0.f;
#pragma unroll
        for (int i = 0; i < 4; ++i)
            atomicAdd(&out[(mbase + lg * 4 + i) * D_ + col], acc[i] + bias);
    }
}

extern "C" void kernel_launch(void* const* d_in, const int* in_sizes, int n_in,
                              void* d_out, int out_size, void* d_ws, size_t ws_size,
                              hipStream_t stream) {
    const float* key   = (const float*)d_in[0];
    const float* value = (const float*)d_in[1];
    const float* query = (const float*)d_in[2];
    const float* Wq = (const float*)d_in[3];
    const float* bq = (const float*)d_in[4];
    const float* Wk = (const float*)d_in[5];
    const float* bk = (const float*)d_in[6];
    const float* Wv = (const float*)d_in[7];
    const float* bv = (const float*)d_in[8];
    const float* Wo = (const float*)d_in[9];
    const float* bo = (const float*)d_in[10];
    float* out = (float*)d_out;

    unsigned short* ws = (unsigned short*)d_ws;
    const size_t QKV_ELEMS = (size_t)T_ * H_ * E_ * D_;  // 8388608
    unsigned short* q_ws = ws;
    unsigned short* k_ws = ws + QKV_ELEMS;
    unsigned short* v_ws = ws + 2 * QKV_ELEMS;            // V^T [T][H][D][E], e-permuted
    unsigned short* att_ws = ws + 3 * QKV_ELEMS;
    unsigned short* wo16_ws = q_ws;                       // q_ws dead after attn

    // bf16 staging lives in the att region (dead until attn writes it)
    unsigned short* xq16 = att_ws;
    unsigned short* xk16 = att_ws + 524288;
    unsigned short* xv16 = att_ws + 1048576;
    unsigned short* wq16 = att_ws + 1572864;
    unsigned short* wk16 = att_ws + 1835008;
    unsigned short* wv16 = att_ws + 2097152;

    cvt6_kernel<<<dim3(1152), 256, 0, stream>>>(query, key, value, Wq, Wk, Wv, att_ws);
    qkv_kernel<<<dim3(32, 16, 3), 256, 0, stream>>>(xq16, xk16, xv16,
                                                    wq16, wk16, wv16,
                                                    bq, bk, bv,
                                                    q_ws, k_ws, v_ws);
    attn_kernel<<<dim3(64, 8), 256, 0, stream>>>(q_ws, k_ws, v_ws, att_ws);
    cvt_kernel<<<dim3(128), 256, 0, stream>>>(Wo, wo16_ws);
    hipMemsetAsync(out, 0, (size_t)out_size * sizeof(float), stream);
    oproj_kernel<<<dim3(256, 4), 256, 0, stream>>>(att_ws, wo16_ws, bo, out);
}

// Round 9
// 109.806 us; speedup vs baseline: 2.7972x; 1.0137x over previous
//
#include <hip/hip_runtime.h>

#define T_ 4
#define E_ 1024
#define H_ 16
#define D_ 128
#define C_ 2048
#define QK_SCALE 0.08838834764831845f
#define LOG2E 1.4426950408889634f

typedef short s16x8 __attribute__((ext_vector_type(8)));
typedef float f32x4 __attribute__((ext_vector_type(4)));

__device__ __forceinline__ unsigned short f2bf(float x) {
    unsigned u = __builtin_bit_cast(unsigned, x);
    u = (u + 0x7FFFu + ((u >> 16) & 1u)) >> 16;
    return (unsigned short)u;
}

__device__ __forceinline__ unsigned cvt_pk(float lo, float hi) {
    unsigned r;
    asm("v_cvt_pk_bf16_f32 %0, %1, %2" : "=v"(r) : "v"(lo), "v"(hi));
    return r;
}

#define MFMA16(a, b, c) __builtin_amdgcn_mfma_f32_16x16x32_bf16((a), (b), (c), 0, 0, 0)

__device__ __forceinline__ void gload_lds16(const unsigned short* g, unsigned short* l) {
    __builtin_amdgcn_global_load_lds(
        (const __attribute__((address_space(1))) unsigned int*)g,
        (__attribute__((address_space(3))) unsigned int*)l, 16, 0, 0);
}

// ---------------- generic f32 -> bf16 convert (2048 elems / block) ----------------
__global__ __launch_bounds__(256) void cvt_kernel(
    const float* __restrict__ src, unsigned short* __restrict__ dst)
{
    const int i = (blockIdx.x * 256 + threadIdx.x) * 8;
    float4 a = *reinterpret_cast<const float4*>(src + i);
    float4 b = *reinterpret_cast<const float4*>(src + i + 4);
    s16x8 r;
    r[0] = (short)f2bf(a.x); r[1] = (short)f2bf(a.y);
    r[2] = (short)f2bf(a.z); r[3] = (short)f2bf(a.w);
    r[4] = (short)f2bf(b.x); r[5] = (short)f2bf(b.y);
    r[6] = (short)f2bf(b.z); r[7] = (short)f2bf(b.w);
    *reinterpret_cast<s16x8*>(dst + i) = r;
}

// ---------------- fused 6-tensor f32 -> bf16 convert ----------------
__global__ __launch_bounds__(256) void cvt6_kernel(
    const float* __restrict__ q, const float* __restrict__ k, const float* __restrict__ v,
    const float* __restrict__ wq, const float* __restrict__ wk, const float* __restrict__ wv,
    unsigned short* __restrict__ base)
{
    const int b = blockIdx.x;
    const float* src;
    unsigned short* dst;
    int lb;
    if (b < 256)       { src = q;  dst = base;            lb = b; }
    else if (b < 512)  { src = k;  dst = base + 524288;   lb = b - 256; }
    else if (b < 768)  { src = v;  dst = base + 1048576;  lb = b - 512; }
    else if (b < 896)  { src = wq; dst = base + 1572864;  lb = b - 768; }
    else if (b < 1024) { src = wk; dst = base + 1835008;  lb = b - 896; }
    else               { src = wv; dst = base + 2097152;  lb = b - 1024; }
    const int i = (lb * 256 + threadIdx.x) * 8;
    float4 a = *reinterpret_cast<const float4*>(src + i);
    float4 c = *reinterpret_cast<const float4*>(src + i + 4);
    s16x8 r;
    r[0] = (short)f2bf(a.x); r[1] = (short)f2bf(a.y);
    r[2] = (short)f2bf(a.z); r[3] = (short)f2bf(a.w);
    r[4] = (short)f2bf(c.x); r[5] = (short)f2bf(c.y);
    r[6] = (short)f2bf(c.z); r[7] = (short)f2bf(c.w);
    *reinterpret_cast<s16x8*>(dst + i) = r;
}

// ---------------- K1: QKV projection (bf16 in, bf16 out) ----------------
// Q,K out: [T][H][E][128] with d stored at position n+8*lr (d=n*16+lr).
// V out: TRANSPOSED [T][H][D][E] with e within-32 permuted:
//   e%32 = 16h+4g+i  stored at  pos%32 = 8g+4h+i.
// Q pre-scaled by QK_SCALE*log2(e).
__global__ __launch_bounds__(256) void qkv_kernel(
    const unsigned short* __restrict__ Xq, const unsigned short* __restrict__ Xk,
    const unsigned short* __restrict__ Xv,
    const unsigned short* __restrict__ Wq_, const unsigned short* __restrict__ Wk_,
    const unsigned short* __restrict__ Wv_,
    const float* __restrict__ bq_, const float* __restrict__ bk_, const float* __restrict__ bv_,
    unsigned short* __restrict__ oq, unsigned short* __restrict__ okk,
    unsigned short* __restrict__ ov)
{
    __shared__ unsigned short Tile[128 * 136];

    const int z = blockIdx.z;
    const unsigned short* X = (z == 0) ? Xq : (z == 1) ? Xk : Xv;
    const unsigned short* W = (z == 0) ? Wq_ : (z == 1) ? Wk_ : Wv_;
    const float* Bv = (z == 0) ? bq_ : (z == 1) ? bk_ : bv_;
    unsigned short* out = (z == 0) ? oq : (z == 1) ? okk : ov;
    const float scale = (z == 0) ? (QK_SCALE * LOG2E) : 1.0f;

    const int tid = threadIdx.x;
    const int w = tid >> 6;
    const int lane = tid & 63;
    const int lr = lane & 15;
    const int lg = lane >> 4;
    const int mbase = blockIdx.x * 128 + w * 32;
    const int nbase = blockIdx.y * 128;

    s16x8 af[2][4];
#pragma unroll
    for (int mi = 0; mi < 2; ++mi)
#pragma unroll
        for (int kc = 0; kc < 4; ++kc)
            af[mi][kc] = *reinterpret_cast<const s16x8*>(
                &X[(mbase + mi * 16 + lr) * D_ + kc * 32 + lg * 8]);

    f32x4 acc[2][8];
#pragma unroll
    for (int mi = 0; mi < 2; ++mi)
#pragma unroll
        for (int n = 0; n < 8; ++n) acc[mi][n] = f32x4{0.f, 0.f, 0.f, 0.f};

#pragma unroll
    for (int n = 0; n < 8; ++n) {
        s16x8 bf[4];
#pragma unroll
        for (int kc = 0; kc < 4; ++kc)
            bf[kc] = *reinterpret_cast<const s16x8*>(
                &W[(nbase + n * 16 + lr) * D_ + kc * 32 + lg * 8]);
#pragma unroll
        for (int mi = 0; mi < 2; ++mi)
#pragma unroll
            for (int kc = 0; kc < 4; ++kc)
                acc[mi][n] = MFMA16(af[mi][kc], bf[kc], acc[mi][n]);
    }

    float bias[8];
#pragma unroll
    for (int n = 0; n < 8; ++n) bias[n] = Bv[nbase + n * 16 + lr];

    if (z < 2) {
#pragma unroll
        for (int mi = 0; mi < 2; ++mi)
#pragma unroll
            for (int i = 0; i < 4; ++i) {
                const int rowl = w * 32 + mi * 16 + lg * 4 + i;
                float v0 = (acc[mi][0][i] + bias[0]) * scale;
                float v1 = (acc[mi][1][i] + bias[1]) * scale;
                float v2 = (acc[mi][2][i] + bias[2]) * scale;
                float v3 = (acc[mi][3][i] + bias[3]) * scale;
                float v4 = (acc[mi][4][i] + bias[4]) * scale;
                float v5 = (acc[mi][5][i] + bias[5]) * scale;
                float v6 = (acc[mi][6][i] + bias[6]) * scale;
                float v7 = (acc[mi][7][i] + bias[7]) * scale;
                union { s16x8 s; unsigned u[4]; } pk;
                pk.u[0] = cvt_pk(v0, v1);
                pk.u[1] = cvt_pk(v2, v3);
                pk.u[2] = cvt_pk(v4, v5);
                pk.u[3] = cvt_pk(v6, v7);
                *reinterpret_cast<s16x8*>(&Tile[rowl * 136 + 8 * lr]) = pk.s;
            }
    } else {
#pragma unroll
        for (int n = 0; n < 8; ++n) {
            union { s16x8 s; unsigned u[4]; } pk;
            pk.u[0] = cvt_pk(acc[0][n][0] + bias[n], acc[0][n][1] + bias[n]);
            pk.u[1] = cvt_pk(acc[0][n][2] + bias[n], acc[0][n][3] + bias[n]);
            pk.u[2] = cvt_pk(acc[1][n][0] + bias[n], acc[1][n][1] + bias[n]);
            pk.u[3] = cvt_pk(acc[1][n][2] + bias[n], acc[1][n][3] + bias[n]);
            *reinterpret_cast<s16x8*>(&Tile[(n * 16 + lr) * 136 + w * 32 + 8 * lg]) = pk.s;
        }
    }
    __syncthreads();

    // wave-contiguous write-out (4 full rows / instruction)
    const int t = (blockIdx.x * 128) >> 10;
    const int e0 = (blockIdx.x * 128) & 1023;
    const int hh = blockIdx.y;
    const int row16 = tid >> 4;
    const int c8 = (tid & 15) * 8;
    if (z < 2) {
        unsigned short* dst = out + (((size_t)(t * H_ + hh) * E_ + e0) * D_);
#pragma unroll
        for (int j = 0; j < 8; ++j) {
            const int row = j * 16 + row16;
            *reinterpret_cast<s16x8*>(dst + (size_t)row * D_ + c8) =
                *reinterpret_cast<const s16x8*>(&Tile[row * 136 + c8]);
        }
    } else {
        unsigned short* dst = out + ((size_t)(t * H_ + hh) * D_) * E_ + e0;
#pragma unroll
        for (int j = 0; j < 8; ++j) {
            const int row = j * 16 + row16;
            *reinterpret_cast<s16x8*>(dst + (size_t)row * E_ + c8) =
                *reinterpret_cast<const s16x8*>(&Tile[row * 136 + c8]);
        }
    }
}

// ---------------- K2: causal flash attention (S^T, 8 waves x 16 q-rows) ----------------
// grid (T*H, 8), 512 thr = 8 waves, each wave one 16-row q-slice of a 128-row
// qblk. qblk map [7,6,5,4,0,1,2,3] -> round-robin pairs (p,p+4) balance CUs.
// All 512 blocks co-resident (64KB LDS, 2/CU) -> 16 waves/CU.
__global__ __launch_bounds__(512, 4) void attn_kernel(
    const unsigned short* __restrict__ Q, const unsigned short* __restrict__ K,
    const unsigned short* __restrict__ Vt, unsigned short* __restrict__ O)
{
    __shared__ unsigned short K_lds[2][64 * 128];   // [kk][c] = K[kv0+kk][c ^ ((kk&7)<<3)]
    __shared__ unsigned short Vt_lds[2][128 * 64];  // [d][p]  = Vperm[d][kv0 + (p ^ ((d&7)<<3))]

    const int tid = threadIdx.x;
    const int w = tid >> 6;
    const int lane = tid & 63;
    const int lr = lane & 15;
    const int g = lane >> 4;
    const int th = blockIdx.x;
    const int t = th >> 4;
    const int h = th & 15;
    const int p = blockIdx.y;
    const int qblk = (p < 4) ? (7 - p) : (p - 4);
    const int q0w = qblk * 128 + w * 16;
    const int nkv = 2 * qblk + 2;

    const unsigned short* Qh = Q + th * (E_ * D_);
    const unsigned short* Kh = K + th * (E_ * D_);
    const unsigned short* Vth = Vt + th * (D_ * E_);

    // Q as B-fragments (cols = q rows), pre-scaled in qkv
    s16x8 qb[4];
#pragma unroll
    for (int kc = 0; kc < 4; ++kc)
        qb[kc] = *reinterpret_cast<const s16x8*>(
            &Qh[(q0w + lr) * D_ + kc * 32 + g * 8]);

    s16x8 ones;
#pragma unroll
    for (int j = 0; j < 8; ++j) ones[j] = (short)0x3F80;

    f32x4 ot[8];
    f32x4 lac;
    float m = -1e30f;
#pragma unroll
    for (int dt = 0; dt < 8; ++dt) ot[dt] = f32x4{0.f, 0.f, 0.f, 0.f};
    lac = f32x4{0.f, 0.f, 0.f, 0.f};

    // prologue: stage tile 0 (2 K-iters + 2 V-iters, 512 threads)
#pragma unroll
    for (int it = 0; it < 2; ++it) {
        const int f = it * 512 + tid;
        const int kk = f >> 4, ck = (f & 15) * 8;
        gload_lds16(&Kh[kk * D_ + (ck ^ ((kk & 7) << 3))], &K_lds[0][f * 8]);
        const int dd = f >> 3, cv = (f & 7) * 8;
        gload_lds16(&Vth[dd * E_ + (cv ^ ((dd & 7) << 3))], &Vt_lds[0][f * 8]);
    }

    int cur = 0;
    for (int kb = 0; kb < nkv; ++kb) {
        const int kv0 = kb * 64;
        __syncthreads();

        if (kb + 1 < nkv) {
            const int kv1 = kv0 + 64;
#pragma unroll
            for (int it = 0; it < 2; ++it) {
                const int f = it * 512 + tid;
                const int kk = f >> 4, ck = (f & 15) * 8;
                gload_lds16(&Kh[(kv1 + kk) * D_ + (ck ^ ((kk & 7) << 3))],
                            &K_lds[cur ^ 1][f * 8]);
                const int dd = f >> 3, cv = (f & 7) * 8;
                gload_lds16(&Vth[dd * E_ + kv1 + (cv ^ ((dd & 7) << 3))],
                            &Vt_lds[cur ^ 1][f * 8]);
            }
        }

        if (kv0 <= q0w + 15) {
            const unsigned short* Kb = K_lds[cur];
            const unsigned short* Vb = Vt_lds[cur];
            const int key = (lr & 7) << 3;

            // S^T[kv][q]: 4 kv tiles x 1 q tile
            f32x4 st[4];
            __builtin_amdgcn_s_setprio(1);
#pragma unroll
            for (int kvi = 0; kvi < 4; ++kvi) {
                s16x8 kf[4];
#pragma unroll
                for (int kc = 0; kc < 4; ++kc)
                    kf[kc] = *reinterpret_cast<const s16x8*>(
                        &Kb[(kvi * 16 + lr) * 128 + ((kc * 32 + g * 8) ^ key)]);
                f32x4 a = f32x4{0.f, 0.f, 0.f, 0.f};
#pragma unroll
                for (int kc = 0; kc < 4; ++kc) a = MFMA16(kf[kc], qb[kc], a);
                st[kvi] = a;
            }
            __builtin_amdgcn_s_setprio(0);

            // causal mask: only diagonal tiles (wave-uniform branch)
            if (kv0 + 63 > q0w) {
                const int q = q0w + lr;
#pragma unroll
                for (int kvi = 0; kvi < 4; ++kvi)
#pragma unroll
                    for (int i = 0; i < 4; ++i) {
                        const int kv = kv0 + kvi * 16 + g * 4 + i;
                        if (kv > q) st[kvi][i] = -1e30f;
                    }
            }

            // per-q-column max: lane-local over 16 vals, then xor-16/32
            float a0 = fmaxf(fmaxf(st[0][0], st[0][1]), fmaxf(st[0][2], st[0][3]));
            float a1 = fmaxf(fmaxf(st[1][0], st[1][1]), fmaxf(st[1][2], st[1][3]));
            float a2 = fmaxf(fmaxf(st[2][0], st[2][1]), fmaxf(st[2][2], st[2][3]));
            float a3 = fmaxf(fmaxf(st[3][0], st[3][1]), fmaxf(st[3][2], st[3][3]));
            float pm = fmaxf(fmaxf(a0, a1), fmaxf(a2, a3));
            pm = fmaxf(pm, __shfl_xor(pm, 16));
            pm = fmaxf(pm, __shfl_xor(pm, 32));

            // defer-max: rescale only when max grew past threshold
            if (__any(pm > m + 8.f)) {
                const float mn = fmaxf(m, pm);
                const float esc = exp2f(m - mn);
                m = mn;
                lac *= esc;
#pragma unroll
                for (int dt = 0; dt < 8; ++dt) ot[dt] *= esc;
            }

            // P^T -> bf16 B-frags in registers
            s16x8 pb[2];
#pragma unroll
            for (int kc = 0; kc < 2; ++kc) {
                float e0 = exp2f(st[2 * kc][0] - m);
                float e1 = exp2f(st[2 * kc][1] - m);
                float e2 = exp2f(st[2 * kc][2] - m);
                float e3 = exp2f(st[2 * kc][3] - m);
                float f0 = exp2f(st[2 * kc + 1][0] - m);
                float f1 = exp2f(st[2 * kc + 1][1] - m);
                float f2 = exp2f(st[2 * kc + 1][2] - m);
                float f3 = exp2f(st[2 * kc + 1][3] - m);
                union { s16x8 s; unsigned u[4]; } pk;
                pk.u[0] = cvt_pk(e0, e1);
                pk.u[1] = cvt_pk(e2, e3);
                pk.u[2] = cvt_pk(f0, f1);
                pk.u[3] = cvt_pk(f2, f3);
                pb[kc] = pk.s;
            }

            // row-sum via ones-MFMA
            lac = MFMA16(ones, pb[0], lac);
            lac = MFMA16(ones, pb[1], lac);

            // O^T += V^T @ P^T  (A-frag: ONE b128 read, conflict-free)
            __builtin_amdgcn_s_setprio(1);
#pragma unroll
            for (int dt = 0; dt < 8; ++dt) {
                const int rb = (dt * 16 + lr) * 64;
#pragma unroll
                for (int kc = 0; kc < 2; ++kc) {
                    s16x8 va = *reinterpret_cast<const s16x8*>(
                        &Vb[rb + ((kc * 32 + 8 * g) ^ key)]);
                    ot[dt] = MFMA16(va, pb[kc], ot[dt]);
                }
            }
            __builtin_amdgcn_s_setprio(0);
        }
        cur ^= 1;
    }

    // epilogue: lane holds q=q0w+lr, d=dt*16+g*4+i -> b64 stores
    unsigned short* Ob = O + (size_t)t * E_ * C_ + h * D_;
    const float rl = 1.0f / lac[0];
    const int q = q0w + lr;
#pragma unroll
    for (int dt = 0; dt < 8; ++dt) {
        uint2 val;
        val.x = cvt_pk(ot[dt][0] * rl, ot[dt][1] * rl);
        val.y = cvt_pk(ot[dt][2] * rl, ot[dt][3] * rl);
        *reinterpret_cast<uint2*>(&Ob[(size_t)q * C_ + dt * 16 + 4 * g]) = val;
    }
}

// ---------------- K3: output projection (M=4096, N=128, K=2048) ----------------
// grid (256, 8): x = 16-row tile, y = K-eighth. Partial sums via atomicAdd
// into zeroed output; bias added by the y==0 segment only.
__global__ __launch_bounds__(256) void oproj_kernel(
    const unsigned short* __restrict__ A, const unsigned short* __restrict__ Wo16,
    const float* __restrict__ bo, float* __restrict__ out)
{
    const int tid = threadIdx.x;
    const int w = tid >> 6;
    const int lane = tid & 63;
    const int lr = lane & 15;
    const int lg = lane >> 4;
    const int mbase = blockIdx.x * 16;
    const int ncol = w * 32;
    const int k0 = blockIdx.y * 256;

    f32x4 acc0 = f32x4{0.f, 0.f, 0.f, 0.f};
    f32x4 acc1 = f32x4{0.f, 0.f, 0.f, 0.f};
    const unsigned short* Arow = A + (size_t)(mbase + lr) * C_ + k0;
    const unsigned short* W0 = Wo16 + (size_t)(ncol + lr) * C_ + k0;
    const unsigned short* W1 = Wo16 + (size_t)(ncol + 16 + lr) * C_ + k0;

#pragma unroll 8
    for (int kb = 0; kb < 8; ++kb) {
        const int ko = kb * 32 + lg * 8;
        s16x8 af = *reinterpret_cast<const s16x8*>(Arow + ko);
        s16x8 b0 = *reinterpret_cast<const s16x8*>(W0 + ko);
        s16x8 b1 = *reinterpret_cast<const s16x8*>(W1 + ko);
        acc0 = MFMA16(af, b0, acc0);
        acc1 = MFMA16(af, b1, acc1);
    }

#pragma unroll
    for (int n = 0; n < 2; ++n) {
        const f32x4 acc = n ? acc1 : acc0;
        const int col = ncol + n * 16 + lr;
        const float bias = (blockIdx.y == 0) ? bo[col] : 0.f;
#pragma unroll
        for (int i = 0; i < 4; ++i)
            atomicAdd(&out[(mbase + lg * 4 + i) * D_ + col], acc[i] + bias);
    }
}

extern "C" void kernel_launch(void* const* d_in, const int* in_sizes, int n_in,
                              void* d_out, int out_size, void* d_ws, size_t ws_size,
                              hipStream_t stream) {
    const float* key   = (const float*)d_in[0];
    const float* value = (const float*)d_in[1];
    const float* query = (const float*)d_in[2];
    const float* Wq = (const float*)d_in[3];
    const float* bq = (const float*)d_in[4];
    const float* Wk = (const float*)d_in[5];
    const float* bk = (const float*)d_in[6];
    const float* Wv = (const float*)d_in[7];
    const float* bv = (const float*)d_in[8];
    const float* Wo = (const float*)d_in[9];
    const float* bo = (const float*)d_in[10];
    float* out = (float*)d_out;

    unsigned short* ws = (unsigned short*)d_ws;
    const size_t QKV_ELEMS = (size_t)T_ * H_ * E_ * D_;  // 8388608
    unsigned short* q_ws = ws;
    unsigned short* k_ws = ws + QKV_ELEMS;
    unsigned short* v_ws = ws + 2 * QKV_ELEMS;            // V^T [T][H][D][E], e-permuted
    unsigned short* att_ws = ws + 3 * QKV_ELEMS;
    unsigned short* wo16_ws = q_ws;                       // q_ws dead after attn

    // bf16 staging lives in the att region (dead until attn writes it)
    unsigned short* xq16 = att_ws;
    unsigned short* xk16 = att_ws + 524288;
    unsigned short* xv16 = att_ws + 1048576;
    unsigned short* wq16 = att_ws + 1572864;
    unsigned short* wk16 = att_ws + 1835008;
    unsigned short* wv16 = att_ws + 2097152;

    cvt6_kernel<<<dim3(1152), 256, 0, stream>>>(query, key, value, Wq, Wk, Wv, att_ws);
    qkv_kernel<<<dim3(32, 16, 3), 256, 0, stream>>>(xq16, xk16, xv16,
                                                    wq16, wk16, wv16,
                                                    bq, bk, bv,
                                                    q_ws, k_ws, v_ws);
    attn_kernel<<<dim3(64, 8), 512, 0, stream>>>(q_ws, k_ws, v_ws, att_ws);
    cvt_kernel<<<dim3(128), 256, 0, stream>>>(Wo, wo16_ws);
    hipMemsetAsync(out, 0, (size_t)out_size * sizeof(float), stream);
    oproj_kernel<<<dim3(256, 8), 256, 0, stream>>>(att_ws, wo16_ws, bo, out);
}